// Round 11
// baseline (206.991 us; speedup 1.0000x reference)
//
#include <hip/hip_runtime.h>
#include <cstdint>
#include <cstddef>

typedef _Float16 f16;
typedef _Float16 f16x4 __attribute__((ext_vector_type(4)));
typedef _Float16 f16x8 __attribute__((ext_vector_type(8)));
typedef float f32x4 __attribute__((ext_vector_type(4)));
typedef float f32x16 __attribute__((ext_vector_type(16)));

#define DEVI __device__ __forceinline__

DEVI void gload_lds16(const void* g, void* l) {
  __builtin_amdgcn_global_load_lds(
      (const __attribute__((address_space(1))) void*)g,
      (__attribute__((address_space(3))) void*)l, 16, 0, 0);
}

DEVI float fexp2(float x) { return __builtin_amdgcn_exp2f(x); }

// ---------------- f32 -> f16 convert, 8 elems/thread ----------------
__global__ void k_cvt(const float* __restrict__ in, f16* __restrict__ out, int n) {
  int i = (blockIdx.x * 256 + threadIdx.x) * 8;
  if (i >= n) return;
  const float4* p = reinterpret_cast<const float4*>(in + i);
  float4 a = p[0], b = p[1];
  f16x8 o;
  o[0] = (f16)a.x; o[1] = (f16)a.y; o[2] = (f16)a.z; o[3] = (f16)a.w;
  o[4] = (f16)b.x; o[5] = (f16)b.y; o[6] = (f16)b.z; o[7] = (f16)b.w;
  *reinterpret_cast<f16x8*>(out + i) = o;
}

// 4 weight matrices in one launch (1 MB f32 each)
__global__ void k_cvtw(const float* __restrict__ w0, const float* __restrict__ w1,
                       const float* __restrict__ w2, const float* __restrict__ w3,
                       f16* __restrict__ o0, f16* __restrict__ o1,
                       f16* __restrict__ o2, f16* __restrict__ o3) {
  int seg = blockIdx.x >> 9;
  const float* in = (seg == 0) ? w0 : (seg == 1) ? w1 : (seg == 2) ? w2 : w3;
  f16* out = (seg == 0) ? o0 : (seg == 1) ? o1 : (seg == 2) ? o2 : o3;
  int i = ((blockIdx.x & 511) * 256 + threadIdx.x) * 8;
  const float4* p = reinterpret_cast<const float4*>(in + i);
  float4 a = p[0], b = p[1];
  f16x8 o;
  o[0] = (f16)a.x; o[1] = (f16)a.y; o[2] = (f16)a.z; o[3] = (f16)a.w;
  o[4] = (f16)b.x; o[5] = (f16)b.y; o[6] = (f16)b.z; o[7] = (f16)b.w;
  *reinterpret_cast<f16x8*>(out + i) = o;
}

// ---------------- misc prep: sincos table + packed attention mask --------
__global__ void k_misc(const int* __restrict__ amask,
                       const int* __restrict__ pE, const int* __restrict__ pSkip,
                       float2* __restrict__ sctab, unsigned* __restrict__ pmask) {
  int E = *pE, skip = *pSkip;
  if (blockIdx.x < 256) {
    int idx = blockIdx.x * 256 + threadIdx.x;
    int s = idx >> 5, t = idx & 31;
    float c = 1.0f, sn = 0.0f;
    if (!(skip && s < E)) {
      int p = skip ? s - E : s;
      float inv_freq = powf(10000.0f, -(float)t / 32.0f);
      sincosf((float)p * inv_freq, &sn, &c);
    }
    sctab[idx] = make_float2(c, sn);
  } else {
    int tid = threadIdx.x;
    int b = tid >> 6, jb = tid & 63;
    unsigned bits = 0;
    for (int j = 0; j < 32; ++j)
      bits |= (amask[b * 2048 + jb * 32 + j] != 0 ? 1u : 0u) << j;
    pmask[tid] = bits;
  }
}

// ---------------- GEMM: C[M,N] = A[M,K] * B[N,K]^T ----------------
// 1-D grid, m-slab XCD map: xcd = lid&7 owns m-panels [xcd*8, xcd*8+8).
// MODE 1: f32 row-major out (Wo projection), grid 512.
// MODE 2: fused QKV, grid 1536. z=0: rope -> Qf direct. z=1: rope -> Kx
//   fragment-major via LDS repack. z=2: -> Vx tau-permuted via LDS repack.
template<int MODE>
__global__ __launch_bounds__(256) void k_gemm(
    const f16* __restrict__ A,
    const f16* __restrict__ B0, const f16* __restrict__ B1, const f16* __restrict__ B2,
    void* __restrict__ C0, void* __restrict__ C1, void* __restrict__ C2,
    const float2* __restrict__ sctab) {
  constexpr int K = 1024, N = 1024;
  __shared__ char smem[32768];
  f16* As = (f16*)smem;
  f16* Bs = (f16*)(smem + 16384);
  const int lid = blockIdx.x;
  const int xcd = lid & 7;
  int z, mp, n;
  if (MODE == 1) {
    int c = lid >> 3;
    mp = xcd * 8 + (c & 7);
    n = c >> 3;
    z = 0;
  } else {
    int c = lid >> 3;
    mp = xcd * 8 + (c & 7);
    n = (c >> 3) & 7;
    z = c >> 6;
  }
  const f16* B = (z == 0) ? B0 : ((z == 1) ? B1 : B2);
  const int tid = threadIdx.x;
  const int lane = tid & 63;
  const int wave = tid >> 6;
  const int wr = wave >> 1, wc = wave & 1;
  const int l15 = lane & 15, l4 = lane >> 4;
  const int m0 = mp * 128, n0 = n * 128;
  const int srow = tid >> 3, su = tid & 7;

  f32x4 acc[4][4] = {};

  for (int kt = 0; kt < K; kt += 64) {
    __syncthreads();
#pragma unroll
    for (int q = 0; q < 4; ++q) {
      int r = q * 32 + srow;
      int ce = (su ^ (r & 7)) * 8;
      gload_lds16(A + (size_t)(m0 + r) * K + kt + ce,
                  (char*)As + (q * 256 + (tid & 192)) * 16);
    }
#pragma unroll
    for (int q = 0; q < 4; ++q) {
      int r = q * 32 + srow;
      int ce = (su ^ (r & 7)) * 8;
      gload_lds16(B + (size_t)(n0 + r) * K + kt + ce,
                  (char*)Bs + (q * 256 + (tid & 192)) * 16);
    }
    __syncthreads();
#pragma unroll
    for (int kk = 0; kk < 2; ++kk) {
      f16x8 af[4], bf[4];
#pragma unroll
      for (int mi = 0; mi < 4; ++mi) {
        int r = wr * 64 + mi * 16 + l15;
        int u = (kk * 4 + l4) ^ (r & 7);
        af[mi] = *reinterpret_cast<const f16x8*>((const char*)As + r * 128 + u * 16);
      }
#pragma unroll
      for (int ni = 0; ni < 4; ++ni) {
        int r = wc * 64 + ni * 16 + l15;
        int u = (kk * 4 + l4) ^ (r & 7);
        bf[ni] = *reinterpret_cast<const f16x8*>((const char*)Bs + r * 128 + u * 16);
      }
#pragma unroll
      for (int mi = 0; mi < 4; ++mi)
#pragma unroll
        for (int ni = 0; ni < 4; ++ni)
          acc[mi][ni] = __builtin_amdgcn_mfma_f32_16x16x32_f16(af[mi], bf[ni], acc[mi][ni], 0, 0, 0);
    }
  }

  if (MODE == 1) {
#pragma unroll
    for (int mi = 0; mi < 4; ++mi)
#pragma unroll
      for (int ni = 0; ni < 4; ++ni)
#pragma unroll
        for (int r = 0; r < 4; ++r) {
          int row = m0 + wr * 64 + mi * 16 + l4 * 4 + r;
          int col = n0 + wc * 64 + ni * 16 + l15;
          ((float*)C0)[(size_t)row * N + col] = acc[mi][ni][r];
        }
    return;
  }

  f16* Qf = (f16*)C0;
  f16* Kx = (f16*)C1;
  f16* Vx = (f16*)C2;

  if (z == 0) {
#pragma unroll
    for (int mi = 0; mi < 4; ++mi)
#pragma unroll
      for (int ni = 0; ni < 4; ++ni)
#pragma unroll
        for (int r = 0; r < 4; ++r) {
          int row = m0 + wr * 64 + mi * 16 + l4 * 4 + r;
          int col = n0 + wc * 64 + ni * 16 + l15;
          int s = row & 2047;
          int dd = col & 63;
          float val = acc[mi][ni][r];
          float pv = __shfl_xor(val, 1, 64);
          float2 cs = sctab[s * 32 + (dd >> 1)];
          val = val * cs.x + ((l15 & 1) ? pv * cs.y : -pv * cs.y);
          Qf[(size_t)row * 1024 + col] = (f16)val;
        }
    return;
  }

  __syncthreads();  // done reading As/Bs; reuse as C-tile
  f16* Ct = (f16*)smem;

  if (z == 1) {
#pragma unroll
    for (int mi = 0; mi < 4; ++mi)
#pragma unroll
      for (int ni = 0; ni < 4; ++ni)
#pragma unroll
        for (int r = 0; r < 4; ++r) {
          int sl = wr * 64 + mi * 16 + l4 * 4 + r;
          int cl = wc * 64 + ni * 16 + l15;
          int s = (m0 + sl) & 2047;
          float val = acc[mi][ni][r];
          float pv = __shfl_xor(val, 1, 64);
          float2 cs = sctab[s * 32 + ((cl & 63) >> 1)];
          val = val * cs.x + ((l15 & 1) ? pv * cs.y : -pv * cs.y);
          *(f16*)((char*)Ct + sl * 256 + (((cl >> 3) ^ (sl & 15)) << 4) + (cl & 7) * 2) = (f16)val;
        }
    __syncthreads();
#pragma unroll
    for (int it = 0; it < 8; ++it) {
      int it2 = wave * 8 + it;
      int h2 = it2 >> 4, k16 = (it2 >> 2) & 3, hf = (it2 >> 1) & 1, sh = it2 & 1;
      int sl = sh * 64 + lane;
      int cl = h2 * 64 + k16 * 16 + hf * 8;
      f16x8 v = *(const f16x8*)((const char*)Ct + sl * 256 + (((cl >> 3) ^ (sl & 15)) << 4));
      int sg = m0 + sl;
      int b = sg >> 11, s = sg & 2047;
      int h = (n0 >> 6) + h2;
      *reinterpret_cast<f16x8*>(
          Kx + (((size_t)((b * 16 + h) * 4 + k16) * 2048 + s) << 4) + hf * 8) = v;
    }
  } else {
#pragma unroll
    for (int mi = 0; mi < 4; ++mi)
#pragma unroll
      for (int ni = 0; ni < 4; ++ni) {
        int sl = wr * 64 + mi * 16 + l4 * 4;
        int cl = wc * 64 + ni * 16 + l15;
        f16x4 pk;
#pragma unroll
        for (int r = 0; r < 4; ++r) pk[r] = (f16)acc[mi][ni][r];
        *(f16x4*)((char*)Ct + cl * 256 + ((((sl >> 2) ^ (cl & 31))) << 3)) = pk;
      }
    __syncthreads();
#pragma unroll
    for (int it = 0; it < 8; ++it) {
      int it2 = wave * 8 + it;
      int hh = it2 >> 4, dh2 = (it2 >> 3) & 1, kvb = (it2 >> 1) & 3, hf = it2 & 1;
      int kh = lane >> 5, ql = lane & 31;
      int cl = hh * 64 + dh2 * 32 + ql;
      int s0 = kvb * 32 + kh * 16 + hf * 4;
      f16x4 a = *(const f16x4*)((const char*)Ct + cl * 256 + (((s0 >> 2) ^ (cl & 31)) << 3));
      f16x4 c = *(const f16x4*)((const char*)Ct + cl * 256 + ((((s0 + 8) >> 2) ^ (cl & 31)) << 3));
      f16x8 v;
#pragma unroll
      for (int e = 0; e < 4; ++e) { v[e] = a[e]; v[4 + e] = c[e]; }
      int b = m0 >> 11;
      int kvblk = ((m0 & 2047) >> 5) + kvb;
      int h = (n0 >> 6) + hh;
      size_t idx = (((size_t)(((b * 16 + h) * 64 + kvblk) * 2 + dh2) * 2 + kh) * 32 + ql) << 4;
      *reinterpret_cast<f16x8*>(Vx + idx + hf * 8) = v;
    }
  }
}

// ---------------- flash attention: balanced 2-wave KV-split --------------
// grid 2048 = (bh, pair pr). Block does q-tiles pr and 63-pr sequentially
// (uniform ~65 tiles/block). Within a q-tile the 2 waves split the KV loop
// (jb = wave, wave+2, ...) with private online-softmax state, merged via a
// small LDS exchange at tile end. 32x32 swapped MFMA, in-register P.
__global__ __launch_bounds__(128) void k_attn(
    const f16* __restrict__ Q, const f16* __restrict__ Kx, const f16* __restrict__ Vx,
    const unsigned* __restrict__ pmask, const int* __restrict__ pE,
    f16* __restrict__ AO) {
  __shared__ float sM[2][64];
  __shared__ float sL[64];
  __shared__ float sAcc[64][33];   // wave1's scaled acc; stride 33 = 2-way-free
  const int lid = (blockIdx.x & 7) * 256 + (blockIdx.x >> 3);  // XCD swizzle
  const int bh = lid >> 5;
  const int pr = lid & 31;
  const int b = bh >> 4, h = bh & 15;
  const int wave = threadIdx.x >> 6;
  const int lane = threadIdx.x & 63;
  const int ql = lane & 31;
  const int hf = lane >> 5;
  const int E = *pE;
  const int ekv = (E + 31) >> 5;
  constexpr float SCALE = 0.125f * 1.44269504088896f;  // dh^-0.5 * log2(e)

  auto DOTILE = [&](int qt) {
    const int irow = qt * 32 + ql;
    f16x8 qf[4];
    {
      const f16* qp = Q + ((size_t)(b * 2048 + irow)) * 1024 + h * 64 + hf * 8;
#pragma unroll
      for (int k16 = 0; k16 < 4; ++k16) {
        f16x8 v = *reinterpret_cast<const f16x8*>(qp + k16 * 16);
#pragma unroll
        for (int e = 0; e < 8; ++e) v[e] = (f16)((float)v[e] * SCALE);
        qf[k16] = v;
      }
    }
    f32x16 acc0 = {}, acc1 = {};
    float mq = -1e30f, lq = 0.f;
    int nkv = qt + 1;
    if (ekv > nkv) nkv = ekv;
    if (nkv > 64) nkv = 64;

    f16x8 kf[4];
    if (wave < nkv) {
#pragma unroll
      for (int k16 = 0; k16 < 4; ++k16)
        kf[k16] = *reinterpret_cast<const f16x8*>(
            Kx + (((size_t)((bh * 4 + k16) * 2048 + wave * 32 + ql)) << 4) + hf * 8);
    }

    for (int jb = wave; jb < nkv; jb += 2) {
      const int kv0 = jb * 32;
      f32x16 st = {};
#pragma unroll
      for (int k16 = 0; k16 < 4; ++k16)
        st = __builtin_amdgcn_mfma_f32_32x32x16_f16(kf[k16], qf[k16], st, 0, 0, 0);
      f16x8 vf[4];
#pragma unroll
      for (int dh2 = 0; dh2 < 2; ++dh2)
#pragma unroll
        for (int kh = 0; kh < 2; ++kh)
          vf[dh2 * 2 + kh] = *reinterpret_cast<const f16x8*>(
              Vx + (((size_t)((((bh * 64 + jb) * 2 + dh2) * 2 + kh) * 32 + ql)) << 4) + hf * 8);
      unsigned pm = pmask[b * 64 + jb];
      if (jb + 2 < nkv) {
#pragma unroll
        for (int k16 = 0; k16 < 4; ++k16)
          kf[k16] = *reinterpret_cast<const f16x8*>(
              Kx + (((size_t)((bh * 4 + k16) * 2048 + kv0 + 64 + ql)) << 4) + hf * 8);
      }
      bool full = ((jb < qt) || ((jb + 1) * 32 <= E)) && (pm == 0xffffffffu);
      if (!full) {
#pragma unroll
        for (int r = 0; r < 16; ++r) {
          int kvl = (r & 3) + 8 * (r >> 2) + 4 * hf;
          int jcol = kv0 + kvl;
          bool vis = ((jcol <= irow) || (jcol < E)) && (((pm >> kvl) & 1u) != 0);
          st[r] = vis ? st[r] : -1e30f;
        }
      }
      // max tree as max3 triples (clang fuses fmax(fmax(a,b),c) -> v_max3)
      float t0 = fmaxf(fmaxf(st[0], st[1]), st[2]);
      float t1 = fmaxf(fmaxf(st[3], st[4]), st[5]);
      float t2 = fmaxf(fmaxf(st[6], st[7]), st[8]);
      float t3 = fmaxf(fmaxf(st[9], st[10]), st[11]);
      float t4 = fmaxf(fmaxf(st[12], st[13]), st[14]);
      float mt = fmaxf(fmaxf(t0, t1), t2);
      mt = fmaxf(fmaxf(mt, t3), fmaxf(t4, st[15]));
      mt = fmaxf(mt, __shfl_xor(mt, 32, 64));
      if (!__all(mt - mq <= 8.0f)) {
        float mnew = fmaxf(mq, mt);
        float alpha = fexp2(mq - mnew);
        lq *= alpha;
#pragma unroll
        for (int r = 0; r < 16; ++r) { acc0[r] *= alpha; acc1[r] *= alpha; }
        mq = mnew;
      }
      float p[16];
      float ps = 0.f;
#pragma unroll
      for (int r = 0; r < 16; ++r) { p[r] = fexp2(st[r] - mq); ps += p[r]; }
      lq += ps;
      union PF { unsigned u[4]; f16x8 v; } pf0, pf1;
#pragma unroll
      for (int t = 0; t < 4; ++t) {
        pf0.u[t] = __builtin_bit_cast(unsigned, __builtin_amdgcn_cvt_pkrtz(p[2 * t], p[2 * t + 1]));
        pf1.u[t] = __builtin_bit_cast(unsigned, __builtin_amdgcn_cvt_pkrtz(p[8 + 2 * t], p[9 + 2 * t]));
      }
      acc0 = __builtin_amdgcn_mfma_f32_32x32x16_f16(vf[0], pf0.v, acc0, 0, 0, 0);
      acc0 = __builtin_amdgcn_mfma_f32_32x32x16_f16(vf[1], pf1.v, acc0, 0, 0, 0);
      acc1 = __builtin_amdgcn_mfma_f32_32x32x16_f16(vf[2], pf0.v, acc1, 0, 0, 0);
      acc1 = __builtin_amdgcn_mfma_f32_32x32x16_f16(vf[3], pf1.v, acc1, 0, 0, 0);
    }

    // cross-wave merge: m* = max; each wave scales own state; wave1 publishes
    sM[wave][lane] = mq;
    __syncthreads();
    float mo = sM[wave ^ 1][lane];
    float ms = fmaxf(mq, mo);
    float sc = fexp2(mq - ms);
    lq *= sc;
#pragma unroll
    for (int r = 0; r < 16; ++r) { acc0[r] *= sc; acc1[r] *= sc; }
    if (wave) {
      sL[lane] = lq;
#pragma unroll
      for (int r = 0; r < 16; ++r) {
        sAcc[lane][r] = acc0[r];
        sAcc[lane][16 + r] = acc1[r];
      }
    }
    __syncthreads();
    if (!wave) {
      lq += sL[lane];
#pragma unroll
      for (int r = 0; r < 16; ++r) {
        acc0[r] += sAcc[lane][r];
        acc1[r] += sAcc[lane][16 + r];
      }
      float ltot = lq + __shfl_xor(lq, 32, 64);
      float inv = 1.0f / ltot;
      f16* op = AO + ((size_t)(b * 2048 + irow)) * 1024 + h * 64;
#pragma unroll
      for (int t = 0; t < 4; ++t) {
        int d0 = 8 * t + 4 * hf;
        f16x4 o0, o1;
#pragma unroll
        for (int e = 0; e < 4; ++e) {
          o0[e] = (f16)(acc0[4 * t + e] * inv);
          o1[e] = (f16)(acc1[4 * t + e] * inv);
        }
        *reinterpret_cast<f16x4*>(op + d0) = o0;
        *reinterpret_cast<f16x4*>(op + 32 + d0) = o1;
      }
    }
    __syncthreads();  // LDS reuse guard for the next q-tile
  };

  DOTILE(pr);
  DOTILE(63 - pr);
}

// ---------------- launcher ----------------
extern "C" void kernel_launch(void* const* d_in, const int* in_sizes, int n_in,
                              void* d_out, int out_size, void* d_ws, size_t ws_size,
                              hipStream_t stream) {
  const float* x  = (const float*)d_in[0];
  const float* Wq = (const float*)d_in[1];
  const float* Wk = (const float*)d_in[2];
  const float* Wv = (const float*)d_in[3];
  const float* Wo = (const float*)d_in[4];
  const int* amask = (const int*)d_in[5];
  const int* pE    = (const int*)d_in[6];
  const int* pSkip = (const int*)d_in[7];

  char* ws = (char*)d_ws;
  f16* xb   = (f16*)(ws);                   // x f16; dead after gemm<2> -> AO
  f16* Wqb  = (f16*)(ws + (16u << 20));
  f16* Wkb  = (f16*)(ws + (18u << 20));
  f16* Wvb  = (f16*)(ws + (20u << 20));
  f16* Wob  = (f16*)(ws + (22u << 20));
  f16* Qf   = (f16*)(ws + (24u << 20));
  f16* Kx   = (f16*)(ws + (40u << 20));
  f16* Vx   = (f16*)(ws + (56u << 20));
  float2* sctab = (float2*)(ws + (72u << 20));   // 512 KB
  unsigned* pmask = (unsigned*)(ws + (73u << 20));
  f16* AO   = xb;

  k_misc<<<257, 256, 0, stream>>>(amask, pE, pSkip, sctab, pmask);
  k_cvt<<<4096, 256, 0, stream>>>(x, xb, 8388608);
  k_cvtw<<<2048, 256, 0, stream>>>(Wq, Wk, Wv, Wo, Wqb, Wkb, Wvb, Wob);
  // QKV projections fused with RoPE + fragment-major repack (m-slab XCD map)
  k_gemm<2><<<1536, 256, 0, stream>>>(xb, Wqb, Wkb, Wvb, Qf, Kx, Vx, sctab);
  k_attn<<<2048, 128, 0, stream>>>(Qf, Kx, Vx, pmask, pE, AO);
  // output projection -> fp32 d_out
  k_gemm<1><<<512, 256, 0, stream>>>(AO, Wob, Wob, Wob, d_out, d_out, d_out, nullptr);
}

// Round 12
// 205.016 us; speedup vs baseline: 1.0096x; 1.0096x over previous
//
#include <hip/hip_runtime.h>
#include <cstdint>
#include <cstddef>

typedef _Float16 f16;
typedef _Float16 f16x4 __attribute__((ext_vector_type(4)));
typedef _Float16 f16x8 __attribute__((ext_vector_type(8)));
typedef float f32x4 __attribute__((ext_vector_type(4)));
typedef float f32x16 __attribute__((ext_vector_type(16)));

#define DEVI __device__ __forceinline__

DEVI void gload_lds16(const void* g, void* l) {
  __builtin_amdgcn_global_load_lds(
      (const __attribute__((address_space(1))) void*)g,
      (__attribute__((address_space(3))) void*)l, 16, 0, 0);
}

DEVI float fexp2(float x) { return __builtin_amdgcn_exp2f(x); }

// ---------------- f32 -> f16 convert, 8 elems/thread ----------------
__global__ void k_cvt(const float* __restrict__ in, f16* __restrict__ out, int n) {
  int i = (blockIdx.x * 256 + threadIdx.x) * 8;
  if (i >= n) return;
  const float4* p = reinterpret_cast<const float4*>(in + i);
  float4 a = p[0], b = p[1];
  f16x8 o;
  o[0] = (f16)a.x; o[1] = (f16)a.y; o[2] = (f16)a.z; o[3] = (f16)a.w;
  o[4] = (f16)b.x; o[5] = (f16)b.y; o[6] = (f16)b.z; o[7] = (f16)b.w;
  *reinterpret_cast<f16x8*>(out + i) = o;
}

// 4 weight matrices in one launch (1 MB f32 each)
__global__ void k_cvtw(const float* __restrict__ w0, const float* __restrict__ w1,
                       const float* __restrict__ w2, const float* __restrict__ w3,
                       f16* __restrict__ o0, f16* __restrict__ o1,
                       f16* __restrict__ o2, f16* __restrict__ o3) {
  int seg = blockIdx.x >> 9;
  const float* in = (seg == 0) ? w0 : (seg == 1) ? w1 : (seg == 2) ? w2 : w3;
  f16* out = (seg == 0) ? o0 : (seg == 1) ? o1 : (seg == 2) ? o2 : o3;
  int i = ((blockIdx.x & 511) * 256 + threadIdx.x) * 8;
  const float4* p = reinterpret_cast<const float4*>(in + i);
  float4 a = p[0], b = p[1];
  f16x8 o;
  o[0] = (f16)a.x; o[1] = (f16)a.y; o[2] = (f16)a.z; o[3] = (f16)a.w;
  o[4] = (f16)b.x; o[5] = (f16)b.y; o[6] = (f16)b.z; o[7] = (f16)b.w;
  *reinterpret_cast<f16x8*>(out + i) = o;
}

// ---------------- misc prep: sincos table + packed attention mask --------
__global__ void k_misc(const int* __restrict__ amask,
                       const int* __restrict__ pE, const int* __restrict__ pSkip,
                       float2* __restrict__ sctab, unsigned* __restrict__ pmask) {
  int E = *pE, skip = *pSkip;
  if (blockIdx.x < 256) {
    int idx = blockIdx.x * 256 + threadIdx.x;
    int s = idx >> 5, t = idx & 31;
    float c = 1.0f, sn = 0.0f;
    if (!(skip && s < E)) {
      int p = skip ? s - E : s;
      float inv_freq = powf(10000.0f, -(float)t / 32.0f);
      sincosf((float)p * inv_freq, &sn, &c);
    }
    sctab[idx] = make_float2(c, sn);
  } else {
    int tid = threadIdx.x;
    int b = tid >> 6, jb = tid & 63;
    unsigned bits = 0;
    for (int j = 0; j < 32; ++j)
      bits |= (amask[b * 2048 + jb * 32 + j] != 0 ? 1u : 0u) << j;
    pmask[tid] = bits;
  }
}

// ---------------- GEMM: C[M,N] = A[M,K] * B[N,K]^T ----------------
// 2-phase K-loop (T3-min): BK=32, double-buffered LDS (2x8KB A + 2x8KB B =
// 32KB total, occupancy unchanged). Per iter: STAGE(next) -> ds_read+MFMA(cur)
// -> ONE __syncthreads (vmcnt drain lands after compute, not before).
// 1-D grid, m-slab XCD map: xcd = lid&7 owns m-panels [xcd*8, xcd*8+8).
// MODE 1: f32 row-major out (Wo projection), grid 512.
// MODE 2: fused QKV, grid 1536. z=0: rope -> Qf. z=1: rope -> Kx frag-major.
//   z=2: -> Vx tau-permuted frag-major (both via LDS repack).
template<int MODE>
__global__ __launch_bounds__(256) void k_gemm(
    const f16* __restrict__ A,
    const f16* __restrict__ B0, const f16* __restrict__ B1, const f16* __restrict__ B2,
    void* __restrict__ C0, void* __restrict__ C1, void* __restrict__ C2,
    const float2* __restrict__ sctab) {
  constexpr int K = 1024, N = 1024;
  __shared__ char smem[32768];   // [0,16K): As dbuf, [16K,32K): Bs dbuf
  const int lid = blockIdx.x;
  const int xcd = lid & 7;
  int z, mp, n;
  if (MODE == 1) {
    int c = lid >> 3;
    mp = xcd * 8 + (c & 7);
    n = c >> 3;
    z = 0;
  } else {
    int c = lid >> 3;
    mp = xcd * 8 + (c & 7);
    n = (c >> 3) & 7;
    z = c >> 6;
  }
  const f16* B = (z == 0) ? B0 : ((z == 1) ? B1 : B2);
  const int tid = threadIdx.x;
  const int lane = tid & 63;
  const int wave = tid >> 6;
  const int wr = wave >> 1, wc = wave & 1;
  const int l15 = lane & 15, l4 = lane >> 4;
  const int m0 = mp * 128, n0 = n * 128;

  // staging geometry: thread -> (row r = tid>>2, unit u = tid&3), q in {0,1}
  // stored LDS unit u holds global col-unit (u ^ (r&3))  [bank swizzle]
  const int sr = tid >> 2, su = tid & 3;
  const int ce = (su ^ (sr & 3)) * 8;        // (64+sr)&3 == sr&3
  const f16* gA0 = A + (size_t)(m0 + sr) * K + ce;
  const f16* gA1 = gA0 + (size_t)64 * K;
  const f16* gB0 = B + (size_t)(n0 + sr) * K + ce;
  const f16* gB1 = gB0 + (size_t)64 * K;
  const int ldsLane = (tid & 192) * 16;      // wave-uniform base part

  auto STAGE = [&](int bb, int kt) {
    gload_lds16(gA0 + kt, smem + bb * 8192 + ldsLane);
    gload_lds16(gA1 + kt, smem + bb * 8192 + 4096 + ldsLane);
    gload_lds16(gB0 + kt, smem + 16384 + bb * 8192 + ldsLane);
    gload_lds16(gB1 + kt, smem + 16384 + bb * 8192 + 4096 + ldsLane);
  };

  f32x4 acc[4][4] = {};

  STAGE(0, 0);
  __syncthreads();
  for (int t = 0; t < 32; ++t) {
    const int cur = t & 1;
    if (t + 1 < 32) STAGE(cur ^ 1, (t + 1) * 32);
    f16x8 af[4], bf[4];
#pragma unroll
    for (int mi = 0; mi < 4; ++mi) {
      int r = wr * 64 + mi * 16 + l15;
      af[mi] = *reinterpret_cast<const f16x8*>(
          smem + cur * 8192 + r * 64 + ((l4 ^ (r & 3)) * 16));
    }
#pragma unroll
    for (int ni = 0; ni < 4; ++ni) {
      int r = wc * 64 + ni * 16 + l15;
      bf[ni] = *reinterpret_cast<const f16x8*>(
          smem + 16384 + cur * 8192 + r * 64 + ((l4 ^ (r & 3)) * 16));
    }
#pragma unroll
    for (int mi = 0; mi < 4; ++mi)
#pragma unroll
      for (int ni = 0; ni < 4; ++ni)
        acc[mi][ni] = __builtin_amdgcn_mfma_f32_16x16x32_f16(af[mi], bf[ni], acc[mi][ni], 0, 0, 0);
    __syncthreads();
  }

  if (MODE == 1) {
#pragma unroll
    for (int mi = 0; mi < 4; ++mi)
#pragma unroll
      for (int ni = 0; ni < 4; ++ni)
#pragma unroll
        for (int r = 0; r < 4; ++r) {
          int row = m0 + wr * 64 + mi * 16 + l4 * 4 + r;
          int col = n0 + wc * 64 + ni * 16 + l15;
          ((float*)C0)[(size_t)row * N + col] = acc[mi][ni][r];
        }
    return;
  }

  f16* Qf = (f16*)C0;
  f16* Kx = (f16*)C1;
  f16* Vx = (f16*)C2;

  if (z == 0) {
#pragma unroll
    for (int mi = 0; mi < 4; ++mi)
#pragma unroll
      for (int ni = 0; ni < 4; ++ni)
#pragma unroll
        for (int r = 0; r < 4; ++r) {
          int row = m0 + wr * 64 + mi * 16 + l4 * 4 + r;
          int col = n0 + wc * 64 + ni * 16 + l15;
          int s = row & 2047;
          int dd = col & 63;
          float val = acc[mi][ni][r];
          float pv = __shfl_xor(val, 1, 64);
          float2 cs = sctab[s * 32 + (dd >> 1)];
          val = val * cs.x + ((l15 & 1) ? pv * cs.y : -pv * cs.y);
          Qf[(size_t)row * 1024 + col] = (f16)val;
        }
    return;
  }

  __syncthreads();  // done with staging buffers; reuse smem as C-tile
  f16* Ct = (f16*)smem;

  if (z == 1) {
#pragma unroll
    for (int mi = 0; mi < 4; ++mi)
#pragma unroll
      for (int ni = 0; ni < 4; ++ni)
#pragma unroll
        for (int r = 0; r < 4; ++r) {
          int sl = wr * 64 + mi * 16 + l4 * 4 + r;
          int cl = wc * 64 + ni * 16 + l15;
          int s = (m0 + sl) & 2047;
          float val = acc[mi][ni][r];
          float pv = __shfl_xor(val, 1, 64);
          float2 cs = sctab[s * 32 + ((cl & 63) >> 1)];
          val = val * cs.x + ((l15 & 1) ? pv * cs.y : -pv * cs.y);
          *(f16*)((char*)Ct + sl * 256 + (((cl >> 3) ^ (sl & 15)) << 4) + (cl & 7) * 2) = (f16)val;
        }
    __syncthreads();
#pragma unroll
    for (int it = 0; it < 8; ++it) {
      int it2 = wave * 8 + it;
      int h2 = it2 >> 4, k16 = (it2 >> 2) & 3, hf = (it2 >> 1) & 1, sh = it2 & 1;
      int sl = sh * 64 + lane;
      int cl = h2 * 64 + k16 * 16 + hf * 8;
      f16x8 v = *(const f16x8*)((const char*)Ct + sl * 256 + (((cl >> 3) ^ (sl & 15)) << 4));
      int sg = m0 + sl;
      int b = sg >> 11, s = sg & 2047;
      int h = (n0 >> 6) + h2;
      *reinterpret_cast<f16x8*>(
          Kx + (((size_t)((b * 16 + h) * 4 + k16) * 2048 + s) << 4) + hf * 8) = v;
    }
  } else {
#pragma unroll
    for (int mi = 0; mi < 4; ++mi)
#pragma unroll
      for (int ni = 0; ni < 4; ++ni) {
        int sl = wr * 64 + mi * 16 + l4 * 4;
        int cl = wc * 64 + ni * 16 + l15;
        f16x4 pk;
#pragma unroll
        for (int r = 0; r < 4; ++r) pk[r] = (f16)acc[mi][ni][r];
        *(f16x4*)((char*)Ct + cl * 256 + ((((sl >> 2) ^ (cl & 31))) << 3)) = pk;
      }
    __syncthreads();
#pragma unroll
    for (int it = 0; it < 8; ++it) {
      int it2 = wave * 8 + it;
      int hh = it2 >> 4, dh2 = (it2 >> 3) & 1, kvb = (it2 >> 1) & 3, hf = it2 & 1;
      int kh = lane >> 5, ql = lane & 31;
      int cl = hh * 64 + dh2 * 32 + ql;
      int s0 = kvb * 32 + kh * 16 + hf * 4;
      f16x4 a = *(const f16x4*)((const char*)Ct + cl * 256 + (((s0 >> 2) ^ (cl & 31)) << 3));
      f16x4 c = *(const f16x4*)((const char*)Ct + cl * 256 + ((((s0 + 8) >> 2) ^ (cl & 31)) << 3));
      f16x8 v;
#pragma unroll
      for (int e = 0; e < 4; ++e) { v[e] = a[e]; v[4 + e] = c[e]; }
      int b = m0 >> 11;
      int kvblk = ((m0 & 2047) >> 5) + kvb;
      int h = (n0 >> 6) + hh;
      size_t idx = (((size_t)(((b * 16 + h) * 64 + kvblk) * 2 + dh2) * 2 + kh) * 32 + ql) << 4;
      *reinterpret_cast<f16x8*>(Vx + idx + hf * 8) = v;
    }
  }
}

// ---------------- flash attention (r10-exact): 32x32 swapped MFMA --------
__global__ __launch_bounds__(64) void k_attn(
    const f16* __restrict__ Q, const f16* __restrict__ Kx, const f16* __restrict__ Vx,
    const unsigned* __restrict__ pmask, const int* __restrict__ pE,
    f16* __restrict__ AO) {
  const int lid = (blockIdx.x & 7) * 512 + (blockIdx.x >> 3);  // XCD swizzle (4096%8==0)
  const int bh = lid >> 6;
  const int qt = 63 - (lid & 63);                              // heavy blocks first
  const int b = bh >> 4, h = bh & 15;
  const int lane = threadIdx.x;
  const int ql = lane & 31;
  const int hf = lane >> 5;
  const int E = *pE;
  const int irow = qt * 32 + ql;
  constexpr float SCALE = 0.125f * 1.44269504088896f;  // dh^-0.5 * log2(e)

  f16x8 qf[4];
  {
    const f16* qp = Q + ((size_t)(b * 2048 + irow)) * 1024 + h * 64 + hf * 8;
#pragma unroll
    for (int k16 = 0; k16 < 4; ++k16) {
      f16x8 v = *reinterpret_cast<const f16x8*>(qp + k16 * 16);
#pragma unroll
      for (int e = 0; e < 8; ++e) v[e] = (f16)((float)v[e] * SCALE);
      qf[k16] = v;
    }
  }

  f32x16 acc0 = {}, acc1 = {};
  float mq = -1e30f, lq = 0.f;

  int nkv = qt + 1;
  int ekv = (E + 31) >> 5;
  if (ekv > nkv) nkv = ekv;
  if (nkv > 64) nkv = 64;

  f16x8 kf[4];
#pragma unroll
  for (int k16 = 0; k16 < 4; ++k16)
    kf[k16] = *reinterpret_cast<const f16x8*>(
        Kx + (((size_t)((bh * 4 + k16) * 2048 + ql)) << 4) + hf * 8);

  for (int jb = 0; jb < nkv; ++jb) {
    const int kv0 = jb * 32;
    f32x16 st = {};
#pragma unroll
    for (int k16 = 0; k16 < 4; ++k16)
      st = __builtin_amdgcn_mfma_f32_32x32x16_f16(kf[k16], qf[k16], st, 0, 0, 0);
    f16x8 vf[4];
#pragma unroll
    for (int dh2 = 0; dh2 < 2; ++dh2)
#pragma unroll
      for (int kh = 0; kh < 2; ++kh)
        vf[dh2 * 2 + kh] = *reinterpret_cast<const f16x8*>(
            Vx + (((size_t)((((bh * 64 + jb) * 2 + dh2) * 2 + kh) * 32 + ql)) << 4) + hf * 8);
    unsigned pm = pmask[b * 64 + jb];
    if (jb + 1 < nkv) {
#pragma unroll
      for (int k16 = 0; k16 < 4; ++k16)
        kf[k16] = *reinterpret_cast<const f16x8*>(
            Kx + (((size_t)((bh * 4 + k16) * 2048 + kv0 + 32 + ql)) << 4) + hf * 8);
    }
    bool full = ((jb < qt) || ((jb + 1) * 32 <= E)) && (pm == 0xffffffffu);
    if (!full) {
#pragma unroll
      for (int r = 0; r < 16; ++r) {
        int kvl = (r & 3) + 8 * (r >> 2) + 4 * hf;
        int jcol = kv0 + kvl;
        bool vis = ((jcol <= irow) || (jcol < E)) && (((pm >> kvl) & 1u) != 0);
        st[r] = vis ? st[r] : -1e30f;
      }
    }
    float m01 = fmaxf(fmaxf(st[0], st[1]), fmaxf(st[2], st[3]));
    float m23 = fmaxf(fmaxf(st[4], st[5]), fmaxf(st[6], st[7]));
    float m45 = fmaxf(fmaxf(st[8], st[9]), fmaxf(st[10], st[11]));
    float m67 = fmaxf(fmaxf(st[12], st[13]), fmaxf(st[14], st[15]));
    float mt = fmaxf(fmaxf(m01, m23), fmaxf(m45, m67));
    mt = fmaxf(mt, __shfl_xor(mt, 32, 64));
    if (!__all(mt - mq <= 8.0f)) {
      float mnew = fmaxf(mq, mt);
      float alpha = fexp2(mq - mnew);
      lq *= alpha;
#pragma unroll
      for (int r = 0; r < 16; ++r) { acc0[r] *= alpha; acc1[r] *= alpha; }
      mq = mnew;
    }
    float p[16];
    float ps = 0.f;
#pragma unroll
    for (int r = 0; r < 16; ++r) { p[r] = fexp2(st[r] - mq); ps += p[r]; }
    lq += ps;
    union PF { unsigned u[4]; f16x8 v; } pf0, pf1;
#pragma unroll
    for (int t = 0; t < 4; ++t) {
      pf0.u[t] = __builtin_bit_cast(unsigned, __builtin_amdgcn_cvt_pkrtz(p[2 * t], p[2 * t + 1]));
      pf1.u[t] = __builtin_bit_cast(unsigned, __builtin_amdgcn_cvt_pkrtz(p[8 + 2 * t], p[9 + 2 * t]));
    }
    acc0 = __builtin_amdgcn_mfma_f32_32x32x16_f16(vf[0], pf0.v, acc0, 0, 0, 0);
    acc0 = __builtin_amdgcn_mfma_f32_32x32x16_f16(vf[1], pf1.v, acc0, 0, 0, 0);
    acc1 = __builtin_amdgcn_mfma_f32_32x32x16_f16(vf[2], pf0.v, acc1, 0, 0, 0);
    acc1 = __builtin_amdgcn_mfma_f32_32x32x16_f16(vf[3], pf1.v, acc1, 0, 0, 0);
  }

  float ltot = lq + __shfl_xor(lq, 32, 64);
  float inv = 1.0f / ltot;
  f16* op = AO + ((size_t)(b * 2048 + irow)) * 1024 + h * 64;
#pragma unroll
  for (int t = 0; t < 4; ++t) {
    int d0 = 8 * t + 4 * hf;
    f16x4 o0, o1;
#pragma unroll
    for (int e = 0; e < 4; ++e) {
      o0[e] = (f16)(acc0[4 * t + e] * inv);
      o1[e] = (f16)(acc1[4 * t + e] * inv);
    }
    *reinterpret_cast<f16x4*>(op + d0) = o0;
    *reinterpret_cast<f16x4*>(op + 32 + d0) = o1;
  }
}

// ---------------- launcher ----------------
extern "C" void kernel_launch(void* const* d_in, const int* in_sizes, int n_in,
                              void* d_out, int out_size, void* d_ws, size_t ws_size,
                              hipStream_t stream) {
  const float* x  = (const float*)d_in[0];
  const float* Wq = (const float*)d_in[1];
  const float* Wk = (const float*)d_in[2];
  const float* Wv = (const float*)d_in[3];
  const float* Wo = (const float*)d_in[4];
  const int* amask = (const int*)d_in[5];
  const int* pE    = (const int*)d_in[6];
  const int* pSkip = (const int*)d_in[7];

  char* ws = (char*)d_ws;
  f16* xb   = (f16*)(ws);                   // x f16; dead after gemm<2> -> AO
  f16* Wqb  = (f16*)(ws + (16u << 20));
  f16* Wkb  = (f16*)(ws + (18u << 20));
  f16* Wvb  = (f16*)(ws + (20u << 20));
  f16* Wob  = (f16*)(ws + (22u << 20));
  f16* Qf   = (f16*)(ws + (24u << 20));
  f16* Kx   = (f16*)(ws + (40u << 20));
  f16* Vx   = (f16*)(ws + (56u << 20));
  float2* sctab = (float2*)(ws + (72u << 20));   // 512 KB
  unsigned* pmask = (unsigned*)(ws + (73u << 20));
  f16* AO   = xb;

  k_misc<<<257, 256, 0, stream>>>(amask, pE, pSkip, sctab, pmask);
  k_cvt<<<4096, 256, 0, stream>>>(x, xb, 8388608);
  k_cvtw<<<2048, 256, 0, stream>>>(Wq, Wk, Wv, Wo, Wqb, Wkb, Wvb, Wob);
  // QKV projections fused with RoPE + fragment-major repack (m-slab XCD map)
  k_gemm<2><<<1536, 256, 0, stream>>>(xb, Wqb, Wkb, Wvb, Qf, Kx, Vx, sctab);
  k_attn<<<4096, 64, 0, stream>>>(Qf, Kx, Vx, pmask, pE, AO);
  // output projection -> fp32 d_out
  k_gemm<1><<<512, 256, 0, stream>>>(AO, Wob, Wob, Wob, d_out, d_out, d_out, nullptr);
}

// Round 13
// 192.576 us; speedup vs baseline: 1.0749x; 1.0646x over previous
//
#include <hip/hip_runtime.h>
#include <cstdint>
#include <cstddef>

typedef _Float16 f16;
typedef _Float16 f16x4 __attribute__((ext_vector_type(4)));
typedef _Float16 f16x8 __attribute__((ext_vector_type(8)));
typedef float f32x4 __attribute__((ext_vector_type(4)));
typedef float f32x16 __attribute__((ext_vector_type(16)));

#define DEVI __device__ __forceinline__

DEVI void gload_lds16(const void* g, void* l) {
  __builtin_amdgcn_global_load_lds(
      (const __attribute__((address_space(1))) void*)g,
      (__attribute__((address_space(3))) void*)l, 16, 0, 0);
}

DEVI float fexp2(float x) { return __builtin_amdgcn_exp2f(x); }

// ---------------- f32 -> f16 convert, 8 elems/thread ----------------
__global__ void k_cvt(const float* __restrict__ in, f16* __restrict__ out, int n) {
  int i = (blockIdx.x * 256 + threadIdx.x) * 8;
  if (i >= n) return;
  const float4* p = reinterpret_cast<const float4*>(in + i);
  float4 a = p[0], b = p[1];
  f16x8 o;
  o[0] = (f16)a.x; o[1] = (f16)a.y; o[2] = (f16)a.z; o[3] = (f16)a.w;
  o[4] = (f16)b.x; o[5] = (f16)b.y; o[6] = (f16)b.z; o[7] = (f16)b.w;
  *reinterpret_cast<f16x8*>(out + i) = o;
}

// 4 weight matrices in one launch (1 MB f32 each)
__global__ void k_cvtw(const float* __restrict__ w0, const float* __restrict__ w1,
                       const float* __restrict__ w2, const float* __restrict__ w3,
                       f16* __restrict__ o0, f16* __restrict__ o1,
                       f16* __restrict__ o2, f16* __restrict__ o3) {
  int seg = blockIdx.x >> 9;
  const float* in = (seg == 0) ? w0 : (seg == 1) ? w1 : (seg == 2) ? w2 : w3;
  f16* out = (seg == 0) ? o0 : (seg == 1) ? o1 : (seg == 2) ? o2 : o3;
  int i = ((blockIdx.x & 511) * 256 + threadIdx.x) * 8;
  const float4* p = reinterpret_cast<const float4*>(in + i);
  float4 a = p[0], b = p[1];
  f16x8 o;
  o[0] = (f16)a.x; o[1] = (f16)a.y; o[2] = (f16)a.z; o[3] = (f16)a.w;
  o[4] = (f16)b.x; o[5] = (f16)b.y; o[6] = (f16)b.z; o[7] = (f16)b.w;
  *reinterpret_cast<f16x8*>(out + i) = o;
}

// ---------------- misc prep: sincos table + packed attention mask --------
__global__ void k_misc(const int* __restrict__ amask,
                       const int* __restrict__ pE, const int* __restrict__ pSkip,
                       float2* __restrict__ sctab, unsigned* __restrict__ pmask) {
  int E = *pE, skip = *pSkip;
  if (blockIdx.x < 256) {
    int idx = blockIdx.x * 256 + threadIdx.x;
    int s = idx >> 5, t = idx & 31;
    float c = 1.0f, sn = 0.0f;
    if (!(skip && s < E)) {
      int p = skip ? s - E : s;
      float inv_freq = powf(10000.0f, -(float)t / 32.0f);
      sincosf((float)p * inv_freq, &sn, &c);
    }
    sctab[idx] = make_float2(c, sn);
  } else {
    int tid = threadIdx.x;
    int b = tid >> 6, jb = tid & 63;
    unsigned bits = 0;
    for (int j = 0; j < 32; ++j)
      bits |= (amask[b * 2048 + jb * 32 + j] != 0 ? 1u : 0u) << j;
    pmask[tid] = bits;
  }
}

// ---------------- GEMM: C[M,N] = A[M,K] * B[N,K]^T ----------------
// Depth-2 pipeline (T3+T4): BK=32, THREE LDS buffers per matrix (48 KB).
// Iter t stages tile t+2, then s_waitcnt vmcnt(8) (tile-t loads retired,
// t+1/t+2 stay in flight ACROSS the barrier) -> s_barrier -> ds_read+MFMA.
// Loads get ~2 iterations of latency coverage -> no per-iter drain stall.
// Swizzle f(r)=(r>>1)&3 (T2): read slot = 4*(l15&1) + (l4^((l15>>1)&3))
// = 8 slots x 2 lanes = conflict-free (r12's f(r)=r&3 was 4-way, 6.3M).
// WAR safety: buffer staged at iter t was last read at t-1; those ds_reads
// complete ~140cy after barrier(t-1) while the overwrite lands >=500cy
// (>=100cy to issue + >=400cy flight) after the same barrier.
// 1-D grid, m-slab XCD map: xcd = lid&7 owns m-panels [xcd*8, xcd*8+8).
// MODE 1: f32 row-major out (Wo projection), grid 512.
// MODE 2: fused QKV, grid 1536. z=0: rope -> Qf. z=1: rope -> Kx frag-major.
//   z=2: -> Vx tau-permuted frag-major (both via LDS repack).
template<int MODE>
__global__ __launch_bounds__(256) void k_gemm(
    const f16* __restrict__ A,
    const f16* __restrict__ B0, const f16* __restrict__ B1, const f16* __restrict__ B2,
    void* __restrict__ C0, void* __restrict__ C1, void* __restrict__ C2,
    const float2* __restrict__ sctab) {
  constexpr int K = 1024, N = 1024;
  __shared__ char smem[49152];   // [0,24K): As x3, [24K,48K): Bs x3
  const int lid = blockIdx.x;
  const int xcd = lid & 7;
  int z, mp, n;
  if (MODE == 1) {
    int c = lid >> 3;
    mp = xcd * 8 + (c & 7);
    n = c >> 3;
    z = 0;
  } else {
    int c = lid >> 3;
    mp = xcd * 8 + (c & 7);
    n = (c >> 3) & 7;
    z = c >> 6;
  }
  const f16* B = (z == 0) ? B0 : ((z == 1) ? B1 : B2);
  const int tid = threadIdx.x;
  const int lane = tid & 63;
  const int wave = tid >> 6;
  const int wr = wave >> 1, wc = wave & 1;
  const int l15 = lane & 15, l4 = lane >> 4;
  const int m0 = mp * 128, n0 = n * 128;

  // staging: thread -> (row sr = tid>>2, unit su = tid&3); LDS unit su
  // holds global col-unit su ^ ((sr>>1)&3).  (sr+64)>>1 ≡ sr>>1 (mod 4).
  const int sr = tid >> 2, su = tid & 3;
  const int ce = (su ^ ((sr >> 1) & 3)) * 8;
  const f16* gA0 = A + (size_t)(m0 + sr) * K + ce;
  const f16* gA1 = gA0 + (size_t)64 * K;
  const f16* gB0 = B + (size_t)(n0 + sr) * K + ce;
  const f16* gB1 = gB0 + (size_t)64 * K;
  const int ldsLane = (tid & 192) * 16;      // wave-uniform base part

  auto STAGE = [&](int bb, int kt) {
    gload_lds16(gA0 + kt, smem + bb * 8192 + ldsLane);
    gload_lds16(gA1 + kt, smem + bb * 8192 + 4096 + ldsLane);
    gload_lds16(gB0 + kt, smem + 24576 + bb * 8192 + ldsLane);
    gload_lds16(gB1 + kt, smem + 24576 + bb * 8192 + 4096 + ldsLane);
  };

  f32x4 acc[4][4] = {};

  STAGE(0, 0);
  STAGE(1, 32);
  for (int t = 0; t < 32; ++t) {
    const int cur = t % 3;
    if (t < 30) {
      STAGE((t + 2) % 3, (t + 2) * 32);
      asm volatile("s_waitcnt vmcnt(8)" ::: "memory");
    } else if (t == 30) {
      asm volatile("s_waitcnt vmcnt(4)" ::: "memory");
    } else {
      asm volatile("s_waitcnt vmcnt(0)" ::: "memory");
    }
    __builtin_amdgcn_s_barrier();
    __builtin_amdgcn_sched_barrier(0);
    f16x8 af[4], bf[4];
#pragma unroll
    for (int mi = 0; mi < 4; ++mi) {
      int r = wr * 64 + mi * 16 + l15;
      af[mi] = *reinterpret_cast<const f16x8*>(
          smem + cur * 8192 + r * 64 + ((l4 ^ ((r >> 1) & 3)) * 16));
    }
#pragma unroll
    for (int ni = 0; ni < 4; ++ni) {
      int r = wc * 64 + ni * 16 + l15;
      bf[ni] = *reinterpret_cast<const f16x8*>(
          smem + 24576 + cur * 8192 + r * 64 + ((l4 ^ ((r >> 1) & 3)) * 16));
    }
#pragma unroll
    for (int mi = 0; mi < 4; ++mi)
#pragma unroll
      for (int ni = 0; ni < 4; ++ni)
        acc[mi][ni] = __builtin_amdgcn_mfma_f32_16x16x32_f16(af[mi], bf[ni], acc[mi][ni], 0, 0, 0);
  }

  if (MODE == 1) {
#pragma unroll
    for (int mi = 0; mi < 4; ++mi)
#pragma unroll
      for (int ni = 0; ni < 4; ++ni)
#pragma unroll
        for (int r = 0; r < 4; ++r) {
          int row = m0 + wr * 64 + mi * 16 + l4 * 4 + r;
          int col = n0 + wc * 64 + ni * 16 + l15;
          ((float*)C0)[(size_t)row * N + col] = acc[mi][ni][r];
        }
    return;
  }

  f16* Qf = (f16*)C0;
  f16* Kx = (f16*)C1;
  f16* Vx = (f16*)C2;

  if (z == 0) {
#pragma unroll
    for (int mi = 0; mi < 4; ++mi)
#pragma unroll
      for (int ni = 0; ni < 4; ++ni)
#pragma unroll
        for (int r = 0; r < 4; ++r) {
          int row = m0 + wr * 64 + mi * 16 + l4 * 4 + r;
          int col = n0 + wc * 64 + ni * 16 + l15;
          int s = row & 2047;
          int dd = col & 63;
          float val = acc[mi][ni][r];
          float pv = __shfl_xor(val, 1, 64);
          float2 cs = sctab[s * 32 + (dd >> 1)];
          val = val * cs.x + ((l15 & 1) ? pv * cs.y : -pv * cs.y);
          Qf[(size_t)row * 1024 + col] = (f16)val;
        }
    return;
  }

  __syncthreads();  // all loads landed (vmcnt(0) at t=31); reuse smem as C-tile
  f16* Ct = (f16*)smem;

  if (z == 1) {
#pragma unroll
    for (int mi = 0; mi < 4; ++mi)
#pragma unroll
      for (int ni = 0; ni < 4; ++ni)
#pragma unroll
        for (int r = 0; r < 4; ++r) {
          int sl = wr * 64 + mi * 16 + l4 * 4 + r;
          int cl = wc * 64 + ni * 16 + l15;
          int s = (m0 + sl) & 2047;
          float val = acc[mi][ni][r];
          float pv = __shfl_xor(val, 1, 64);
          float2 cs = sctab[s * 32 + ((cl & 63) >> 1)];
          val = val * cs.x + ((l15 & 1) ? pv * cs.y : -pv * cs.y);
          *(f16*)((char*)Ct + sl * 256 + (((cl >> 3) ^ (sl & 15)) << 4) + (cl & 7) * 2) = (f16)val;
        }
    __syncthreads();
#pragma unroll
    for (int it = 0; it < 8; ++it) {
      int it2 = wave * 8 + it;
      int h2 = it2 >> 4, k16 = (it2 >> 2) & 3, hf = (it2 >> 1) & 1, sh = it2 & 1;
      int sl = sh * 64 + lane;
      int cl = h2 * 64 + k16 * 16 + hf * 8;
      f16x8 v = *(const f16x8*)((const char*)Ct + sl * 256 + (((cl >> 3) ^ (sl & 15)) << 4));
      int sg = m0 + sl;
      int b = sg >> 11, s = sg & 2047;
      int h = (n0 >> 6) + h2;
      *reinterpret_cast<f16x8*>(
          Kx + (((size_t)((b * 16 + h) * 4 + k16) * 2048 + s) << 4) + hf * 8) = v;
    }
  } else {
#pragma unroll
    for (int mi = 0; mi < 4; ++mi)
#pragma unroll
      for (int ni = 0; ni < 4; ++ni) {
        int sl = wr * 64 + mi * 16 + l4 * 4;
        int cl = wc * 64 + ni * 16 + l15;
        f16x4 pk;
#pragma unroll
        for (int r = 0; r < 4; ++r) pk[r] = (f16)acc[mi][ni][r];
        *(f16x4*)((char*)Ct + cl * 256 + ((((sl >> 2) ^ (cl & 31))) << 3)) = pk;
      }
    __syncthreads();
#pragma unroll
    for (int it = 0; it < 8; ++it) {
      int it2 = wave * 8 + it;
      int hh = it2 >> 4, dh2 = (it2 >> 3) & 1, kvb = (it2 >> 1) & 3, hf = it2 & 1;
      int kh = lane >> 5, ql = lane & 31;
      int cl = hh * 64 + dh2 * 32 + ql;
      int s0 = kvb * 32 + kh * 16 + hf * 4;
      f16x4 a = *(const f16x4*)((const char*)Ct + cl * 256 + (((s0 >> 2) ^ (cl & 31)) << 3));
      f16x4 c = *(const f16x4*)((const char*)Ct + cl * 256 + ((((s0 + 8) >> 2) ^ (cl & 31)) << 3));
      f16x8 v;
#pragma unroll
      for (int e = 0; e < 4; ++e) { v[e] = a[e]; v[4 + e] = c[e]; }
      int b = m0 >> 11;
      int kvblk = ((m0 & 2047) >> 5) + kvb;
      int h = (n0 >> 6) + hh;
      size_t idx = (((size_t)(((b * 16 + h) * 64 + kvblk) * 2 + dh2) * 2 + kh) * 32 + ql) << 4;
      *reinterpret_cast<f16x8*>(Vx + idx + hf * 8) = v;
    }
  }
}

// ---------------- flash attention (r10-exact): 32x32 swapped MFMA --------
__global__ __launch_bounds__(64) void k_attn(
    const f16* __restrict__ Q, const f16* __restrict__ Kx, const f16* __restrict__ Vx,
    const unsigned* __restrict__ pmask, const int* __restrict__ pE,
    f16* __restrict__ AO) {
  const int lid = (blockIdx.x & 7) * 512 + (blockIdx.x >> 3);  // XCD swizzle (4096%8==0)
  const int bh = lid >> 6;
  const int qt = 63 - (lid & 63);                              // heavy blocks first
  const int b = bh >> 4, h = bh & 15;
  const int lane = threadIdx.x;
  const int ql = lane & 31;
  const int hf = lane >> 5;
  const int E = *pE;
  const int irow = qt * 32 + ql;
  constexpr float SCALE = 0.125f * 1.44269504088896f;  // dh^-0.5 * log2(e)

  f16x8 qf[4];
  {
    const f16* qp = Q + ((size_t)(b * 2048 + irow)) * 1024 + h * 64 + hf * 8;
#pragma unroll
    for (int k16 = 0; k16 < 4; ++k16) {
      f16x8 v = *reinterpret_cast<const f16x8*>(qp + k16 * 16);
#pragma unroll
      for (int e = 0; e < 8; ++e) v[e] = (f16)((float)v[e] * SCALE);
      qf[k16] = v;
    }
  }

  f32x16 acc0 = {}, acc1 = {};
  float mq = -1e30f, lq = 0.f;

  int nkv = qt + 1;
  int ekv = (E + 31) >> 5;
  if (ekv > nkv) nkv = ekv;
  if (nkv > 64) nkv = 64;

  f16x8 kf[4];
#pragma unroll
  for (int k16 = 0; k16 < 4; ++k16)
    kf[k16] = *reinterpret_cast<const f16x8*>(
        Kx + (((size_t)((bh * 4 + k16) * 2048 + ql)) << 4) + hf * 8);

  for (int jb = 0; jb < nkv; ++jb) {
    const int kv0 = jb * 32;
    f32x16 st = {};
#pragma unroll
    for (int k16 = 0; k16 < 4; ++k16)
      st = __builtin_amdgcn_mfma_f32_32x32x16_f16(kf[k16], qf[k16], st, 0, 0, 0);
    f16x8 vf[4];
#pragma unroll
    for (int dh2 = 0; dh2 < 2; ++dh2)
#pragma unroll
      for (int kh = 0; kh < 2; ++kh)
        vf[dh2 * 2 + kh] = *reinterpret_cast<const f16x8*>(
            Vx + (((size_t)((((bh * 64 + jb) * 2 + dh2) * 2 + kh) * 32 + ql)) << 4) + hf * 8);
    unsigned pm = pmask[b * 64 + jb];
    if (jb + 1 < nkv) {
#pragma unroll
      for (int k16 = 0; k16 < 4; ++k16)
        kf[k16] = *reinterpret_cast<const f16x8*>(
            Kx + (((size_t)((bh * 4 + k16) * 2048 + kv0 + 32 + ql)) << 4) + hf * 8);
    }
    bool full = ((jb < qt) || ((jb + 1) * 32 <= E)) && (pm == 0xffffffffu);
    if (!full) {
#pragma unroll
      for (int r = 0; r < 16; ++r) {
        int kvl = (r & 3) + 8 * (r >> 2) + 4 * hf;
        int jcol = kv0 + kvl;
        bool vis = ((jcol <= irow) || (jcol < E)) && (((pm >> kvl) & 1u) != 0);
        st[r] = vis ? st[r] : -1e30f;
      }
    }
    float m01 = fmaxf(fmaxf(st[0], st[1]), fmaxf(st[2], st[3]));
    float m23 = fmaxf(fmaxf(st[4], st[5]), fmaxf(st[6], st[7]));
    float m45 = fmaxf(fmaxf(st[8], st[9]), fmaxf(st[10], st[11]));
    float m67 = fmaxf(fmaxf(st[12], st[13]), fmaxf(st[14], st[15]));
    float mt = fmaxf(fmaxf(m01, m23), fmaxf(m45, m67));
    mt = fmaxf(mt, __shfl_xor(mt, 32, 64));
    if (!__all(mt - mq <= 8.0f)) {
      float mnew = fmaxf(mq, mt);
      float alpha = fexp2(mq - mnew);
      lq *= alpha;
#pragma unroll
      for (int r = 0; r < 16; ++r) { acc0[r] *= alpha; acc1[r] *= alpha; }
      mq = mnew;
    }
    float p[16];
    float ps = 0.f;
#pragma unroll
    for (int r = 0; r < 16; ++r) { p[r] = fexp2(st[r] - mq); ps += p[r]; }
    lq += ps;
    union PF { unsigned u[4]; f16x8 v; } pf0, pf1;
#pragma unroll
    for (int t = 0; t < 4; ++t) {
      pf0.u[t] = __builtin_bit_cast(unsigned, __builtin_amdgcn_cvt_pkrtz(p[2 * t], p[2 * t + 1]));
      pf1.u[t] = __builtin_bit_cast(unsigned, __builtin_amdgcn_cvt_pkrtz(p[8 + 2 * t], p[9 + 2 * t]));
    }
    acc0 = __builtin_amdgcn_mfma_f32_32x32x16_f16(vf[0], pf0.v, acc0, 0, 0, 0);
    acc0 = __builtin_amdgcn_mfma_f32_32x32x16_f16(vf[1], pf1.v, acc0, 0, 0, 0);
    acc1 = __builtin_amdgcn_mfma_f32_32x32x16_f16(vf[2], pf0.v, acc1, 0, 0, 0);
    acc1 = __builtin_amdgcn_mfma_f32_32x32x16_f16(vf[3], pf1.v, acc1, 0, 0, 0);
  }

  float ltot = lq + __shfl_xor(lq, 32, 64);
  float inv = 1.0f / ltot;
  f16* op = AO + ((size_t)(b * 2048 + irow)) * 1024 + h * 64;
#pragma unroll
  for (int t = 0; t < 4; ++t) {
    int d0 = 8 * t + 4 * hf;
    f16x4 o0, o1;
#pragma unroll
    for (int e = 0; e < 4; ++e) {
      o0[e] = (f16)(acc0[4 * t + e] * inv);
      o1[e] = (f16)(acc1[4 * t + e] * inv);
    }
    *reinterpret_cast<f16x4*>(op + d0) = o0;
    *reinterpret_cast<f16x4*>(op + 32 + d0) = o1;
  }
}

// ---------------- launcher ----------------
extern "C" void kernel_launch(void* const* d_in, const int* in_sizes, int n_in,
                              void* d_out, int out_size, void* d_ws, size_t ws_size,
                              hipStream_t stream) {
  const float* x  = (const float*)d_in[0];
  const float* Wq = (const float*)d_in[1];
  const float* Wk = (const float*)d_in[2];
  const float* Wv = (const float*)d_in[3];
  const float* Wo = (const float*)d_in[4];
  const int* amask = (const int*)d_in[5];
  const int* pE    = (const int*)d_in[6];
  const int* pSkip = (const int*)d_in[7];

  char* ws = (char*)d_ws;
  f16* xb   = (f16*)(ws);                   // x f16; dead after gemm<2> -> AO
  f16* Wqb  = (f16*)(ws + (16u << 20));
  f16* Wkb  = (f16*)(ws + (18u << 20));
  f16* Wvb  = (f16*)(ws + (20u << 20));
  f16* Wob  = (f16*)(ws + (22u << 20));
  f16* Qf   = (f16*)(ws + (24u << 20));
  f16* Kx   = (f16*)(ws + (40u << 20));
  f16* Vx   = (f16*)(ws + (56u << 20));
  float2* sctab = (float2*)(ws + (72u << 20));   // 512 KB
  unsigned* pmask = (unsigned*)(ws + (73u << 20));
  f16* AO   = xb;

  k_misc<<<257, 256, 0, stream>>>(amask, pE, pSkip, sctab, pmask);
  k_cvt<<<4096, 256, 0, stream>>>(x, xb, 8388608);
  k_cvtw<<<2048, 256, 0, stream>>>(Wq, Wk, Wv, Wo, Wqb, Wkb, Wvb, Wob);
  // QKV projections fused with RoPE + fragment-major repack (m-slab XCD map)
  k_gemm<2><<<1536, 256, 0, stream>>>(xb, Wqb, Wkb, Wvb, Qf, Kx, Vx, sctab);
  k_attn<<<4096, 64, 0, stream>>>(Qf, Kx, Vx, pmask, pE, AO);
  // output projection -> fp32 d_out
  k_gemm<1><<<512, 256, 0, stream>>>(AO, Wob, Wob, Wob, d_out, d_out, d_out, nullptr);
}

// Round 14
// 191.182 us; speedup vs baseline: 1.0827x; 1.0073x over previous
//
#include <hip/hip_runtime.h>
#include <cstdint>
#include <cstddef>

typedef _Float16 f16;
typedef _Float16 f16x4 __attribute__((ext_vector_type(4)));
typedef _Float16 f16x8 __attribute__((ext_vector_type(8)));
typedef float f32x4 __attribute__((ext_vector_type(4)));
typedef float f32x16 __attribute__((ext_vector_type(16)));

#define DEVI __device__ __forceinline__

DEVI void gload_lds16(const void* g, void* l) {
  __builtin_amdgcn_global_load_lds(
      (const __attribute__((address_space(1))) void*)g,
      (__attribute__((address_space(3))) void*)l, 16, 0, 0);
}

DEVI float fexp2(float x) { return __builtin_amdgcn_exp2f(x); }

// ------------- fused prep: x cvt + 4 weight cvt + sctab + pmask ----------
// blocks [0,4096): x f32->f16. [4096,6144): weights. [6144,6400): sctab.
// [6400]: pmask.
__global__ void k_prep(const float* __restrict__ x,
                       const float* __restrict__ w0, const float* __restrict__ w1,
                       const float* __restrict__ w2, const float* __restrict__ w3,
                       f16* __restrict__ xb,
                       f16* __restrict__ o0, f16* __restrict__ o1,
                       f16* __restrict__ o2, f16* __restrict__ o3,
                       const int* __restrict__ amask,
                       const int* __restrict__ pE, const int* __restrict__ pSkip,
                       float2* __restrict__ sctab, unsigned* __restrict__ pmask) {
  int bb = blockIdx.x;
  if (bb < 4096) {
    int i = (bb * 256 + threadIdx.x) * 8;
    const float4* p = reinterpret_cast<const float4*>(x + i);
    float4 a = p[0], b = p[1];
    f16x8 o;
    o[0] = (f16)a.x; o[1] = (f16)a.y; o[2] = (f16)a.z; o[3] = (f16)a.w;
    o[4] = (f16)b.x; o[5] = (f16)b.y; o[6] = (f16)b.z; o[7] = (f16)b.w;
    *reinterpret_cast<f16x8*>(xb + i) = o;
  } else if (bb < 6144) {
    int seg = (bb - 4096) >> 9;
    const float* in = (seg == 0) ? w0 : (seg == 1) ? w1 : (seg == 2) ? w2 : w3;
    f16* out = (seg == 0) ? o0 : (seg == 1) ? o1 : (seg == 2) ? o2 : o3;
    int i = (((bb - 4096) & 511) * 256 + threadIdx.x) * 8;
    const float4* p = reinterpret_cast<const float4*>(in + i);
    float4 a = p[0], b = p[1];
    f16x8 o;
    o[0] = (f16)a.x; o[1] = (f16)a.y; o[2] = (f16)a.z; o[3] = (f16)a.w;
    o[4] = (f16)b.x; o[5] = (f16)b.y; o[6] = (f16)b.z; o[7] = (f16)b.w;
    *reinterpret_cast<f16x8*>(out + i) = o;
  } else if (bb < 6400) {
    int E = *pE, skip = *pSkip;
    int idx = (bb - 6144) * 256 + threadIdx.x;
    int s = idx >> 5, t = idx & 31;
    float c = 1.0f, sn = 0.0f;
    if (!(skip && s < E)) {
      int p = skip ? s - E : s;
      float inv_freq = powf(10000.0f, -(float)t / 32.0f);
      sincosf((float)p * inv_freq, &sn, &c);
    }
    sctab[idx] = make_float2(c, sn);
  } else {
    int tid = threadIdx.x;
    int b = tid >> 6, jb = tid & 63;
    unsigned bits = 0;
    for (int j = 0; j < 32; ++j)
      bits |= (amask[b * 2048 + jb * 32 + j] != 0 ? 1u : 0u) << j;
    pmask[tid] = bits;
  }
}

// ---------------- GEMM: C[M,N] = A[M,K] * B[N,K]^T ----------------
// Depth-2 pipeline (T3+T4): BK=32, THREE LDS buffers per matrix (48 KB).
// Iter t stages tile t+2, then s_waitcnt vmcnt(8) -> s_barrier -> MFMA.
// Swizzle f(r)=(r>>1)&3 (T2): conflict-free wave64 ds_read_b128.
// 1-D grid, m-slab XCD map. MODE 1: f32 out, grid 512. MODE 2: fused QKV,
// grid 1536 (rope->Qf / rope->Kx frag-major / Vx tau frag-major).
template<int MODE>
__global__ __launch_bounds__(256) void k_gemm(
    const f16* __restrict__ A,
    const f16* __restrict__ B0, const f16* __restrict__ B1, const f16* __restrict__ B2,
    void* __restrict__ C0, void* __restrict__ C1, void* __restrict__ C2,
    const float2* __restrict__ sctab) {
  constexpr int K = 1024, N = 1024;
  __shared__ char smem[49152];   // [0,24K): As x3, [24K,48K): Bs x3
  const int lid = blockIdx.x;
  const int xcd = lid & 7;
  int z, mp, n;
  if (MODE == 1) {
    int c = lid >> 3;
    mp = xcd * 8 + (c & 7);
    n = c >> 3;
    z = 0;
  } else {
    int c = lid >> 3;
    mp = xcd * 8 + (c & 7);
    n = (c >> 3) & 7;
    z = c >> 6;
  }
  const f16* B = (z == 0) ? B0 : ((z == 1) ? B1 : B2);
  const int tid = threadIdx.x;
  const int lane = tid & 63;
  const int wave = tid >> 6;
  const int wr = wave >> 1, wc = wave & 1;
  const int l15 = lane & 15, l4 = lane >> 4;
  const int m0 = mp * 128, n0 = n * 128;

  const int sr = tid >> 2, su = tid & 3;
  const int ce = (su ^ ((sr >> 1) & 3)) * 8;
  const f16* gA0 = A + (size_t)(m0 + sr) * K + ce;
  const f16* gA1 = gA0 + (size_t)64 * K;
  const f16* gB0 = B + (size_t)(n0 + sr) * K + ce;
  const f16* gB1 = gB0 + (size_t)64 * K;
  const int ldsLane = (tid & 192) * 16;

  auto STAGE = [&](int bb, int kt) {
    gload_lds16(gA0 + kt, smem + bb * 8192 + ldsLane);
    gload_lds16(gA1 + kt, smem + bb * 8192 + 4096 + ldsLane);
    gload_lds16(gB0 + kt, smem + 24576 + bb * 8192 + ldsLane);
    gload_lds16(gB1 + kt, smem + 24576 + bb * 8192 + 4096 + ldsLane);
  };

  f32x4 acc[4][4] = {};

  STAGE(0, 0);
  STAGE(1, 32);
  for (int t = 0; t < 32; ++t) {
    const int cur = t % 3;
    if (t < 30) {
      STAGE((t + 2) % 3, (t + 2) * 32);
      asm volatile("s_waitcnt vmcnt(8)" ::: "memory");
    } else if (t == 30) {
      asm volatile("s_waitcnt vmcnt(4)" ::: "memory");
    } else {
      asm volatile("s_waitcnt vmcnt(0)" ::: "memory");
    }
    __builtin_amdgcn_s_barrier();
    __builtin_amdgcn_sched_barrier(0);
    f16x8 af[4], bf[4];
#pragma unroll
    for (int mi = 0; mi < 4; ++mi) {
      int r = wr * 64 + mi * 16 + l15;
      af[mi] = *reinterpret_cast<const f16x8*>(
          smem + cur * 8192 + r * 64 + ((l4 ^ ((r >> 1) & 3)) * 16));
    }
#pragma unroll
    for (int ni = 0; ni < 4; ++ni) {
      int r = wc * 64 + ni * 16 + l15;
      bf[ni] = *reinterpret_cast<const f16x8*>(
          smem + 24576 + cur * 8192 + r * 64 + ((l4 ^ ((r >> 1) & 3)) * 16));
    }
#pragma unroll
    for (int mi = 0; mi < 4; ++mi)
#pragma unroll
      for (int ni = 0; ni < 4; ++ni)
        acc[mi][ni] = __builtin_amdgcn_mfma_f32_16x16x32_f16(af[mi], bf[ni], acc[mi][ni], 0, 0, 0);
  }

  if (MODE == 1) {
#pragma unroll
    for (int mi = 0; mi < 4; ++mi)
#pragma unroll
      for (int ni = 0; ni < 4; ++ni)
#pragma unroll
        for (int r = 0; r < 4; ++r) {
          int row = m0 + wr * 64 + mi * 16 + l4 * 4 + r;
          int col = n0 + wc * 64 + ni * 16 + l15;
          ((float*)C0)[(size_t)row * N + col] = acc[mi][ni][r];
        }
    return;
  }

  f16* Qf = (f16*)C0;
  f16* Kx = (f16*)C1;
  f16* Vx = (f16*)C2;

  if (z == 0) {
#pragma unroll
    for (int mi = 0; mi < 4; ++mi)
#pragma unroll
      for (int ni = 0; ni < 4; ++ni)
#pragma unroll
        for (int r = 0; r < 4; ++r) {
          int row = m0 + wr * 64 + mi * 16 + l4 * 4 + r;
          int col = n0 + wc * 64 + ni * 16 + l15;
          int s = row & 2047;
          int dd = col & 63;
          float val = acc[mi][ni][r];
          float pv = __shfl_xor(val, 1, 64);
          float2 cs = sctab[s * 32 + (dd >> 1)];
          val = val * cs.x + ((l15 & 1) ? pv * cs.y : -pv * cs.y);
          Qf[(size_t)row * 1024 + col] = (f16)val;
        }
    return;
  }

  __syncthreads();  // all loads landed; reuse smem as C-tile
  f16* Ct = (f16*)smem;

  if (z == 1) {
#pragma unroll
    for (int mi = 0; mi < 4; ++mi)
#pragma unroll
      for (int ni = 0; ni < 4; ++ni)
#pragma unroll
        for (int r = 0; r < 4; ++r) {
          int sl = wr * 64 + mi * 16 + l4 * 4 + r;
          int cl = wc * 64 + ni * 16 + l15;
          int s = (m0 + sl) & 2047;
          float val = acc[mi][ni][r];
          float pv = __shfl_xor(val, 1, 64);
          float2 cs = sctab[s * 32 + ((cl & 63) >> 1)];
          val = val * cs.x + ((l15 & 1) ? pv * cs.y : -pv * cs.y);
          *(f16*)((char*)Ct + sl * 256 + (((cl >> 3) ^ (sl & 15)) << 4) + (cl & 7) * 2) = (f16)val;
        }
    __syncthreads();
#pragma unroll
    for (int it = 0; it < 8; ++it) {
      int it2 = wave * 8 + it;
      int h2 = it2 >> 4, k16 = (it2 >> 2) & 3, hf = (it2 >> 1) & 1, sh = it2 & 1;
      int sl = sh * 64 + lane;
      int cl = h2 * 64 + k16 * 16 + hf * 8;
      f16x8 v = *(const f16x8*)((const char*)Ct + sl * 256 + (((cl >> 3) ^ (sl & 15)) << 4));
      int sg = m0 + sl;
      int b = sg >> 11, s = sg & 2047;
      int h = (n0 >> 6) + h2;
      *reinterpret_cast<f16x8*>(
          Kx + (((size_t)((b * 16 + h) * 4 + k16) * 2048 + s) << 4) + hf * 8) = v;
    }
  } else {
#pragma unroll
    for (int mi = 0; mi < 4; ++mi)
#pragma unroll
      for (int ni = 0; ni < 4; ++ni) {
        int sl = wr * 64 + mi * 16 + l4 * 4;
        int cl = wc * 64 + ni * 16 + l15;
        f16x4 pk;
#pragma unroll
        for (int r = 0; r < 4; ++r) pk[r] = (f16)acc[mi][ni][r];
        *(f16x4*)((char*)Ct + cl * 256 + ((((sl >> 2) ^ (cl & 31))) << 3)) = pk;
      }
    __syncthreads();
#pragma unroll
    for (int it = 0; it < 8; ++it) {
      int it2 = wave * 8 + it;
      int hh = it2 >> 4, dh2 = (it2 >> 3) & 1, kvb = (it2 >> 1) & 3, hf = it2 & 1;
      int kh = lane >> 5, ql = lane & 31;
      int cl = hh * 64 + dh2 * 32 + ql;
      int s0 = kvb * 32 + kh * 16 + hf * 4;
      f16x4 a = *(const f16x4*)((const char*)Ct + cl * 256 + (((s0 >> 2) ^ (cl & 31)) << 3));
      f16x4 c = *(const f16x4*)((const char*)Ct + cl * 256 + ((((s0 + 8) >> 2) ^ (cl & 31)) << 3));
      f16x8 v;
#pragma unroll
      for (int e = 0; e < 4; ++e) { v[e] = a[e]; v[4 + e] = c[e]; }
      int b = m0 >> 11;
      int kvblk = ((m0 & 2047) >> 5) + kvb;
      int h = (n0 >> 6) + hh;
      size_t idx = (((size_t)(((b * 16 + h) * 64 + kvblk) * 2 + dh2) * 2 + kh) * 32 + ql) << 4;
      *reinterpret_cast<f16x8*>(Vx + idx + hf * 8) = v;
    }
  }
}

// ---------------- flash attention: 4 independent waves per block ----------
// Grid 1024 x 256 threads: block = (bh, qgroup), wave w -> qt = 63-(qg*4+w).
// Packs 4 waves per workgroup to beat the per-CU workgroup cap that limited
// r10's 64-thread blocks to ~16 waves/CU. Waves share bh -> K/V L1 overlap;
// each XCD gets 8 bh (K+V = 4MB = its L2). Body = r10-exact + max3 tree.
__global__ __launch_bounds__(256) void k_attn(
    const f16* __restrict__ Q, const f16* __restrict__ Kx, const f16* __restrict__ Vx,
    const unsigned* __restrict__ pmask, const int* __restrict__ pE,
    f16* __restrict__ AO) {
  const int lid2 = (blockIdx.x & 7) * 128 + (blockIdx.x >> 3);  // XCD swizzle
  const int bh = lid2 >> 4;
  const int wave = threadIdx.x >> 6;
  const int qt = 63 - ((lid2 & 15) * 4 + wave);
  const int b = bh >> 4, h = bh & 15;
  const int lane = threadIdx.x & 63;
  const int ql = lane & 31;
  const int hf = lane >> 5;
  const int E = *pE;
  const int irow = qt * 32 + ql;
  constexpr float SCALE = 0.125f * 1.44269504088896f;  // dh^-0.5 * log2(e)

  f16x8 qf[4];
  {
    const f16* qp = Q + ((size_t)(b * 2048 + irow)) * 1024 + h * 64 + hf * 8;
#pragma unroll
    for (int k16 = 0; k16 < 4; ++k16) {
      f16x8 v = *reinterpret_cast<const f16x8*>(qp + k16 * 16);
#pragma unroll
      for (int e = 0; e < 8; ++e) v[e] = (f16)((float)v[e] * SCALE);
      qf[k16] = v;
    }
  }

  f32x16 acc0 = {}, acc1 = {};
  float mq = -1e30f, lq = 0.f;

  int nkv = qt + 1;
  int ekv = (E + 31) >> 5;
  if (ekv > nkv) nkv = ekv;
  if (nkv > 64) nkv = 64;

  f16x8 kf[4];
#pragma unroll
  for (int k16 = 0; k16 < 4; ++k16)
    kf[k16] = *reinterpret_cast<const f16x8*>(
        Kx + (((size_t)((bh * 4 + k16) * 2048 + ql)) << 4) + hf * 8);

  for (int jb = 0; jb < nkv; ++jb) {
    const int kv0 = jb * 32;
    f32x16 st = {};
#pragma unroll
    for (int k16 = 0; k16 < 4; ++k16)
      st = __builtin_amdgcn_mfma_f32_32x32x16_f16(kf[k16], qf[k16], st, 0, 0, 0);
    f16x8 vf[4];
#pragma unroll
    for (int dh2 = 0; dh2 < 2; ++dh2)
#pragma unroll
      for (int kh = 0; kh < 2; ++kh)
        vf[dh2 * 2 + kh] = *reinterpret_cast<const f16x8*>(
            Vx + (((size_t)((((bh * 64 + jb) * 2 + dh2) * 2 + kh) * 32 + ql)) << 4) + hf * 8);
    unsigned pm = pmask[b * 64 + jb];
    if (jb + 1 < nkv) {
#pragma unroll
      for (int k16 = 0; k16 < 4; ++k16)
        kf[k16] = *reinterpret_cast<const f16x8*>(
            Kx + (((size_t)((bh * 4 + k16) * 2048 + kv0 + 32 + ql)) << 4) + hf * 8);
    }
    bool full = ((jb < qt) || ((jb + 1) * 32 <= E)) && (pm == 0xffffffffu);
    if (!full) {
#pragma unroll
      for (int r = 0; r < 16; ++r) {
        int kvl = (r & 3) + 8 * (r >> 2) + 4 * hf;
        int jcol = kv0 + kvl;
        bool vis = ((jcol <= irow) || (jcol < E)) && (((pm >> kvl) & 1u) != 0);
        st[r] = vis ? st[r] : -1e30f;
      }
    }
    // max tree as max3 triples (clang fuses fmax(fmax(a,b),c) -> v_max3)
    float t0 = fmaxf(fmaxf(st[0], st[1]), st[2]);
    float t1 = fmaxf(fmaxf(st[3], st[4]), st[5]);
    float t2 = fmaxf(fmaxf(st[6], st[7]), st[8]);
    float t3 = fmaxf(fmaxf(st[9], st[10]), st[11]);
    float t4 = fmaxf(fmaxf(st[12], st[13]), st[14]);
    float mt = fmaxf(fmaxf(t0, t1), t2);
    mt = fmaxf(fmaxf(mt, t3), fmaxf(t4, st[15]));
    mt = fmaxf(mt, __shfl_xor(mt, 32, 64));
    if (!__all(mt - mq <= 8.0f)) {
      float mnew = fmaxf(mq, mt);
      float alpha = fexp2(mq - mnew);
      lq *= alpha;
#pragma unroll
      for (int r = 0; r < 16; ++r) { acc0[r] *= alpha; acc1[r] *= alpha; }
      mq = mnew;
    }
    float p[16];
    float ps = 0.f;
#pragma unroll
    for (int r = 0; r < 16; ++r) { p[r] = fexp2(st[r] - mq); ps += p[r]; }
    lq += ps;
    union PF { unsigned u[4]; f16x8 v; } pf0, pf1;
#pragma unroll
    for (int t = 0; t < 4; ++t) {
      pf0.u[t] = __builtin_bit_cast(unsigned, __builtin_amdgcn_cvt_pkrtz(p[2 * t], p[2 * t + 1]));
      pf1.u[t] = __builtin_bit_cast(unsigned, __builtin_amdgcn_cvt_pkrtz(p[8 + 2 * t], p[9 + 2 * t]));
    }
    acc0 = __builtin_amdgcn_mfma_f32_32x32x16_f16(vf[0], pf0.v, acc0, 0, 0, 0);
    acc0 = __builtin_amdgcn_mfma_f32_32x32x16_f16(vf[1], pf1.v, acc0, 0, 0, 0);
    acc1 = __builtin_amdgcn_mfma_f32_32x32x16_f16(vf[2], pf0.v, acc1, 0, 0, 0);
    acc1 = __builtin_amdgcn_mfma_f32_32x32x16_f16(vf[3], pf1.v, acc1, 0, 0, 0);
  }

  float ltot = lq + __shfl_xor(lq, 32, 64);
  float inv = 1.0f / ltot;
  f16* op = AO + ((size_t)(b * 2048 + irow)) * 1024 + h * 64;
#pragma unroll
  for (int t = 0; t < 4; ++t) {
    int d0 = 8 * t + 4 * hf;
    f16x4 o0, o1;
#pragma unroll
    for (int e = 0; e < 4; ++e) {
      o0[e] = (f16)(acc0[4 * t + e] * inv);
      o1[e] = (f16)(acc1[4 * t + e] * inv);
    }
    *reinterpret_cast<f16x4*>(op + d0) = o0;
    *reinterpret_cast<f16x4*>(op + 32 + d0) = o1;
  }
}

// ---------------- launcher ----------------
extern "C" void kernel_launch(void* const* d_in, const int* in_sizes, int n_in,
                              void* d_out, int out_size, void* d_ws, size_t ws_size,
                              hipStream_t stream) {
  const float* x  = (const float*)d_in[0];
  const float* Wq = (const float*)d_in[1];
  const float* Wk = (const float*)d_in[2];
  const float* Wv = (const float*)d_in[3];
  const float* Wo = (const float*)d_in[4];
  const int* amask = (const int*)d_in[5];
  const int* pE    = (const int*)d_in[6];
  const int* pSkip = (const int*)d_in[7];

  char* ws = (char*)d_ws;
  f16* xb   = (f16*)(ws);                   // x f16; dead after gemm<2> -> AO
  f16* Wqb  = (f16*)(ws + (16u << 20));
  f16* Wkb  = (f16*)(ws + (18u << 20));
  f16* Wvb  = (f16*)(ws + (20u << 20));
  f16* Wob  = (f16*)(ws + (22u << 20));
  f16* Qf   = (f16*)(ws + (24u << 20));
  f16* Kx   = (f16*)(ws + (40u << 20));
  f16* Vx   = (f16*)(ws + (56u << 20));
  float2* sctab = (float2*)(ws + (72u << 20));   // 512 KB
  unsigned* pmask = (unsigned*)(ws + (73u << 20));
  f16* AO   = xb;

  // fused: x cvt + weight cvts + sctab + pmask
  k_prep<<<6401, 256, 0, stream>>>(x, Wq, Wk, Wv, Wo, xb, Wqb, Wkb, Wvb, Wob,
                                   amask, pE, pSkip, sctab, pmask);
  // QKV projections fused with RoPE + fragment-major repack (m-slab XCD map)
  k_gemm<2><<<1536, 256, 0, stream>>>(xb, Wqb, Wkb, Wvb, Qf, Kx, Vx, sctab);
  // attention: 4-wave blocks (workgroup-cap fix)
  k_attn<<<1024, 256, 0, stream>>>(Qf, Kx, Vx, pmask, pE, AO);
  // output projection -> fp32 d_out
  k_gemm<1><<<512, 256, 0, stream>>>(AO, Wob, Wob, Wob, d_out, d_out, d_out, nullptr);
}

// Round 15
// 175.614 us; speedup vs baseline: 1.1787x; 1.0886x over previous
//
#include <hip/hip_runtime.h>
#include <cstdint>
#include <cstddef>

typedef _Float16 f16;
typedef _Float16 f16x4 __attribute__((ext_vector_type(4)));
typedef _Float16 f16x8 __attribute__((ext_vector_type(8)));
typedef float f32x4 __attribute__((ext_vector_type(4)));
typedef float f32x16 __attribute__((ext_vector_type(16)));

#define DEVI __device__ __forceinline__

DEVI void gload_lds16(const void* g, void* l) {
  __builtin_amdgcn_global_load_lds(
      (const __attribute__((address_space(1))) void*)g,
      (__attribute__((address_space(3))) void*)l, 16, 0, 0);
}

DEVI float fexp2(float x) { return __builtin_amdgcn_exp2f(x); }

// ------------- fused prep: x cvt + 4 weight cvt + sctab + pmask ----------
__global__ void k_prep(const float* __restrict__ x,
                       const float* __restrict__ w0, const float* __restrict__ w1,
                       const float* __restrict__ w2, const float* __restrict__ w3,
                       f16* __restrict__ xb,
                       f16* __restrict__ o0, f16* __restrict__ o1,
                       f16* __restrict__ o2, f16* __restrict__ o3,
                       const int* __restrict__ amask,
                       const int* __restrict__ pE, const int* __restrict__ pSkip,
                       float2* __restrict__ sctab, unsigned* __restrict__ pmask) {
  int bb = blockIdx.x;
  if (bb < 4096) {
    int i = (bb * 256 + threadIdx.x) * 8;
    const float4* p = reinterpret_cast<const float4*>(x + i);
    float4 a = p[0], b = p[1];
    f16x8 o;
    o[0] = (f16)a.x; o[1] = (f16)a.y; o[2] = (f16)a.z; o[3] = (f16)a.w;
    o[4] = (f16)b.x; o[5] = (f16)b.y; o[6] = (f16)b.z; o[7] = (f16)b.w;
    *reinterpret_cast<f16x8*>(xb + i) = o;
  } else if (bb < 6144) {
    int seg = (bb - 4096) >> 9;
    const float* in = (seg == 0) ? w0 : (seg == 1) ? w1 : (seg == 2) ? w2 : w3;
    f16* out = (seg == 0) ? o0 : (seg == 1) ? o1 : (seg == 2) ? o2 : o3;
    int i = (((bb - 4096) & 511) * 256 + threadIdx.x) * 8;
    const float4* p = reinterpret_cast<const float4*>(in + i);
    float4 a = p[0], b = p[1];
    f16x8 o;
    o[0] = (f16)a.x; o[1] = (f16)a.y; o[2] = (f16)a.z; o[3] = (f16)a.w;
    o[4] = (f16)b.x; o[5] = (f16)b.y; o[6] = (f16)b.z; o[7] = (f16)b.w;
    *reinterpret_cast<f16x8*>(out + i) = o;
  } else if (bb < 6400) {
    int E = *pE, skip = *pSkip;
    int idx = (bb - 6144) * 256 + threadIdx.x;
    int s = idx >> 5, t = idx & 31;
    float c = 1.0f, sn = 0.0f;
    if (!(skip && s < E)) {
      int p = skip ? s - E : s;
      float inv_freq = powf(10000.0f, -(float)t / 32.0f);
      sincosf((float)p * inv_freq, &sn, &c);
    }
    sctab[idx] = make_float2(c, sn);
  } else {
    int tid = threadIdx.x;
    int b = tid >> 6, jb = tid & 63;
    unsigned bits = 0;
    for (int j = 0; j < 32; ++j)
      bits |= (amask[b * 2048 + jb * 32 + j] != 0 ? 1u : 0u) << j;
    pmask[tid] = bits;
  }
}

// ---------------- GEMM: C[M,N] = A[M,K] * B[N,K]^T ----------------
// Depth-2 pipeline (T3+T4): BK=32, THREE LDS buffers per matrix (48 KB).
// Iter t stages tile t+2, then s_waitcnt vmcnt(8) -> s_barrier -> MFMA.
// Swizzle f(r)=(r>>1)&3 (T2): conflict-free wave64 ds_read_b128.
template<int MODE>
__global__ __launch_bounds__(256) void k_gemm(
    const f16* __restrict__ A,
    const f16* __restrict__ B0, const f16* __restrict__ B1, const f16* __restrict__ B2,
    void* __restrict__ C0, void* __restrict__ C1, void* __restrict__ C2,
    const float2* __restrict__ sctab) {
  constexpr int K = 1024, N = 1024;
  __shared__ char smem[49152];   // [0,24K): As x3, [24K,48K): Bs x3
  const int lid = blockIdx.x;
  const int xcd = lid & 7;
  int z, mp, n;
  if (MODE == 1) {
    int c = lid >> 3;
    mp = xcd * 8 + (c & 7);
    n = c >> 3;
    z = 0;
  } else {
    int c = lid >> 3;
    mp = xcd * 8 + (c & 7);
    n = (c >> 3) & 7;
    z = c >> 6;
  }
  const f16* B = (z == 0) ? B0 : ((z == 1) ? B1 : B2);
  const int tid = threadIdx.x;
  const int lane = tid & 63;
  const int wave = tid >> 6;
  const int wr = wave >> 1, wc = wave & 1;
  const int l15 = lane & 15, l4 = lane >> 4;
  const int m0 = mp * 128, n0 = n * 128;

  const int sr = tid >> 2, su = tid & 3;
  const int ce = (su ^ ((sr >> 1) & 3)) * 8;
  const f16* gA0 = A + (size_t)(m0 + sr) * K + ce;
  const f16* gA1 = gA0 + (size_t)64 * K;
  const f16* gB0 = B + (size_t)(n0 + sr) * K + ce;
  const f16* gB1 = gB0 + (size_t)64 * K;
  const int ldsLane = (tid & 192) * 16;

  auto STAGE = [&](int bb, int kt) {
    gload_lds16(gA0 + kt, smem + bb * 8192 + ldsLane);
    gload_lds16(gA1 + kt, smem + bb * 8192 + 4096 + ldsLane);
    gload_lds16(gB0 + kt, smem + 24576 + bb * 8192 + ldsLane);
    gload_lds16(gB1 + kt, smem + 24576 + bb * 8192 + 4096 + ldsLane);
  };

  f32x4 acc[4][4] = {};

  STAGE(0, 0);
  STAGE(1, 32);
  for (int t = 0; t < 32; ++t) {
    const int cur = t % 3;
    if (t < 30) {
      STAGE((t + 2) % 3, (t + 2) * 32);
      asm volatile("s_waitcnt vmcnt(8)" ::: "memory");
    } else if (t == 30) {
      asm volatile("s_waitcnt vmcnt(4)" ::: "memory");
    } else {
      asm volatile("s_waitcnt vmcnt(0)" ::: "memory");
    }
    __builtin_amdgcn_s_barrier();
    __builtin_amdgcn_sched_barrier(0);
    f16x8 af[4], bf[4];
#pragma unroll
    for (int mi = 0; mi < 4; ++mi) {
      int r = wr * 64 + mi * 16 + l15;
      af[mi] = *reinterpret_cast<const f16x8*>(
          smem + cur * 8192 + r * 64 + ((l4 ^ ((r >> 1) & 3)) * 16));
    }
#pragma unroll
    for (int ni = 0; ni < 4; ++ni) {
      int r = wc * 64 + ni * 16 + l15;
      bf[ni] = *reinterpret_cast<const f16x8*>(
          smem + 24576 + cur * 8192 + r * 64 + ((l4 ^ ((r >> 1) & 3)) * 16));
    }
#pragma unroll
    for (int mi = 0; mi < 4; ++mi)
#pragma unroll
      for (int ni = 0; ni < 4; ++ni)
        acc[mi][ni] = __builtin_amdgcn_mfma_f32_16x16x32_f16(af[mi], bf[ni], acc[mi][ni], 0, 0, 0);
  }

  if (MODE == 1) {
#pragma unroll
    for (int mi = 0; mi < 4; ++mi)
#pragma unroll
      for (int ni = 0; ni < 4; ++ni)
#pragma unroll
        for (int r = 0; r < 4; ++r) {
          int row = m0 + wr * 64 + mi * 16 + l4 * 4 + r;
          int col = n0 + wc * 64 + ni * 16 + l15;
          ((float*)C0)[(size_t)row * N + col] = acc[mi][ni][r];
        }
    return;
  }

  f16* Qf = (f16*)C0;
  f16* Kx = (f16*)C1;
  f16* Vx = (f16*)C2;

  if (z == 0) {
#pragma unroll
    for (int mi = 0; mi < 4; ++mi)
#pragma unroll
      for (int ni = 0; ni < 4; ++ni)
#pragma unroll
        for (int r = 0; r < 4; ++r) {
          int row = m0 + wr * 64 + mi * 16 + l4 * 4 + r;
          int col = n0 + wc * 64 + ni * 16 + l15;
          int s = row & 2047;
          int dd = col & 63;
          float val = acc[mi][ni][r];
          float pv = __shfl_xor(val, 1, 64);
          float2 cs = sctab[s * 32 + (dd >> 1)];
          val = val * cs.x + ((l15 & 1) ? pv * cs.y : -pv * cs.y);
          Qf[(size_t)row * 1024 + col] = (f16)val;
        }
    return;
  }

  __syncthreads();  // all loads landed; reuse smem as C-tile
  f16* Ct = (f16*)smem;

  if (z == 1) {
#pragma unroll
    for (int mi = 0; mi < 4; ++mi)
#pragma unroll
      for (int ni = 0; ni < 4; ++ni)
#pragma unroll
        for (int r = 0; r < 4; ++r) {
          int sl = wr * 64 + mi * 16 + l4 * 4 + r;
          int cl = wc * 64 + ni * 16 + l15;
          int s = (m0 + sl) & 2047;
          float val = acc[mi][ni][r];
          float pv = __shfl_xor(val, 1, 64);
          float2 cs = sctab[s * 32 + ((cl & 63) >> 1)];
          val = val * cs.x + ((l15 & 1) ? pv * cs.y : -pv * cs.y);
          *(f16*)((char*)Ct + sl * 256 + (((cl >> 3) ^ (sl & 15)) << 4) + (cl & 7) * 2) = (f16)val;
        }
    __syncthreads();
#pragma unroll
    for (int it = 0; it < 8; ++it) {
      int it2 = wave * 8 + it;
      int h2 = it2 >> 4, k16 = (it2 >> 2) & 3, hf = (it2 >> 1) & 1, sh = it2 & 1;
      int sl = sh * 64 + lane;
      int cl = h2 * 64 + k16 * 16 + hf * 8;
      f16x8 v = *(const f16x8*)((const char*)Ct + sl * 256 + (((cl >> 3) ^ (sl & 15)) << 4));
      int sg = m0 + sl;
      int b = sg >> 11, s = sg & 2047;
      int h = (n0 >> 6) + h2;
      *reinterpret_cast<f16x8*>(
          Kx + (((size_t)((b * 16 + h) * 4 + k16) * 2048 + s) << 4) + hf * 8) = v;
    }
  } else {
#pragma unroll
    for (int mi = 0; mi < 4; ++mi)
#pragma unroll
      for (int ni = 0; ni < 4; ++ni) {
        int sl = wr * 64 + mi * 16 + l4 * 4;
        int cl = wc * 64 + ni * 16 + l15;
        f16x4 pk;
#pragma unroll
        for (int r = 0; r < 4; ++r) pk[r] = (f16)acc[mi][ni][r];
        *(f16x4*)((char*)Ct + cl * 256 + ((((sl >> 2) ^ (cl & 31))) << 3)) = pk;
      }
    __syncthreads();
#pragma unroll
    for (int it = 0; it < 8; ++it) {
      int it2 = wave * 8 + it;
      int hh = it2 >> 4, dh2 = (it2 >> 3) & 1, kvb = (it2 >> 1) & 3, hf = it2 & 1;
      int kh = lane >> 5, ql = lane & 31;
      int cl = hh * 64 + dh2 * 32 + ql;
      int s0 = kvb * 32 + kh * 16 + hf * 4;
      f16x4 a = *(const f16x4*)((const char*)Ct + cl * 256 + (((s0 >> 2) ^ (cl & 31)) << 3));
      f16x4 c = *(const f16x4*)((const char*)Ct + cl * 256 + ((((s0 + 8) >> 2) ^ (cl & 31)) << 3));
      f16x8 v;
#pragma unroll
      for (int e = 0; e < 4; ++e) { v[e] = a[e]; v[4 + e] = c[e]; }
      int b = m0 >> 11;
      int kvblk = ((m0 & 2047) >> 5) + kvb;
      int h = (n0 >> 6) + hh;
      size_t idx = (((size_t)(((b * 16 + h) * 64 + kvblk) * 2 + dh2) * 2 + kh) * 32 + ql) << 4;
      *reinterpret_cast<f16x8*>(Vx + idx + hf * 8) = v;
    }
  }
}

// ---------------- flash attention: uniform-work q-tile pairing ------------
// Grid 2048 x 64 threads (1 wave). Block = (bh, pr); runs the r10-exact
// tile loop twice: qt = 63-pr (heavy) then qt = pr (light) = 65 tiles per
// block, uniform across the grid -> no residency decay tail (all blocks
// finish together). No merge, no extra barriers, VGPR unchanged.
__global__ __launch_bounds__(64) void k_attn(
    const f16* __restrict__ Q, const f16* __restrict__ Kx, const f16* __restrict__ Vx,
    const unsigned* __restrict__ pmask, const int* __restrict__ pE,
    f16* __restrict__ AO) {
  const int lid = (blockIdx.x & 7) * 256 + (blockIdx.x >> 3);  // XCD swizzle (2048%8==0)
  const int bh = lid >> 5;                                     // 8 bh per XCD
  const int pr = lid & 31;
  const int b = bh >> 4, h = bh & 15;
  const int lane = threadIdx.x;
  const int ql = lane & 31;
  const int hf = lane >> 5;
  const int E = *pE;
  const int ekv = (E + 31) >> 5;
  constexpr float SCALE = 0.125f * 1.44269504088896f;  // dh^-0.5 * log2(e)

#pragma unroll 1
  for (int half = 0; half < 2; ++half) {
    const int qt = half ? pr : 63 - pr;
    const int irow = qt * 32 + ql;

    f16x8 qf[4];
    {
      const f16* qp = Q + ((size_t)(b * 2048 + irow)) * 1024 + h * 64 + hf * 8;
#pragma unroll
      for (int k16 = 0; k16 < 4; ++k16) {
        f16x8 v = *reinterpret_cast<const f16x8*>(qp + k16 * 16);
#pragma unroll
        for (int e = 0; e < 8; ++e) v[e] = (f16)((float)v[e] * SCALE);
        qf[k16] = v;
      }
    }

    f32x16 acc0 = {}, acc1 = {};
    float mq = -1e30f, lq = 0.f;

    int nkv = qt + 1;
    if (ekv > nkv) nkv = ekv;
    if (nkv > 64) nkv = 64;

    f16x8 kf[4];
#pragma unroll
    for (int k16 = 0; k16 < 4; ++k16)
      kf[k16] = *reinterpret_cast<const f16x8*>(
          Kx + (((size_t)((bh * 4 + k16) * 2048 + ql)) << 4) + hf * 8);

    for (int jb = 0; jb < nkv; ++jb) {
      const int kv0 = jb * 32;
      f32x16 st = {};
#pragma unroll
      for (int k16 = 0; k16 < 4; ++k16)
        st = __builtin_amdgcn_mfma_f32_32x32x16_f16(kf[k16], qf[k16], st, 0, 0, 0);
      f16x8 vf[4];
#pragma unroll
      for (int dh2 = 0; dh2 < 2; ++dh2)
#pragma unroll
        for (int kh = 0; kh < 2; ++kh)
          vf[dh2 * 2 + kh] = *reinterpret_cast<const f16x8*>(
              Vx + (((size_t)((((bh * 64 + jb) * 2 + dh2) * 2 + kh) * 32 + ql)) << 4) + hf * 8);
      unsigned pm = pmask[b * 64 + jb];
      if (jb + 1 < nkv) {
#pragma unroll
        for (int k16 = 0; k16 < 4; ++k16)
          kf[k16] = *reinterpret_cast<const f16x8*>(
              Kx + (((size_t)((bh * 4 + k16) * 2048 + kv0 + 32 + ql)) << 4) + hf * 8);
      }
      bool full = ((jb < qt) || ((jb + 1) * 32 <= E)) && (pm == 0xffffffffu);
      if (!full) {
#pragma unroll
        for (int r = 0; r < 16; ++r) {
          int kvl = (r & 3) + 8 * (r >> 2) + 4 * hf;
          int jcol = kv0 + kvl;
          bool vis = ((jcol <= irow) || (jcol < E)) && (((pm >> kvl) & 1u) != 0);
          st[r] = vis ? st[r] : -1e30f;
        }
      }
      // max tree as max3 triples (clang fuses fmax(fmax(a,b),c) -> v_max3)
      float t0 = fmaxf(fmaxf(st[0], st[1]), st[2]);
      float t1 = fmaxf(fmaxf(st[3], st[4]), st[5]);
      float t2 = fmaxf(fmaxf(st[6], st[7]), st[8]);
      float t3 = fmaxf(fmaxf(st[9], st[10]), st[11]);
      float t4 = fmaxf(fmaxf(st[12], st[13]), st[14]);
      float mt = fmaxf(fmaxf(t0, t1), t2);
      mt = fmaxf(fmaxf(mt, t3), fmaxf(t4, st[15]));
      mt = fmaxf(mt, __shfl_xor(mt, 32, 64));
      if (!__all(mt - mq <= 8.0f)) {
        float mnew = fmaxf(mq, mt);
        float alpha = fexp2(mq - mnew);
        lq *= alpha;
#pragma unroll
        for (int r = 0; r < 16; ++r) { acc0[r] *= alpha; acc1[r] *= alpha; }
        mq = mnew;
      }
      float p[16];
      float ps = 0.f;
#pragma unroll
      for (int r = 0; r < 16; ++r) { p[r] = fexp2(st[r] - mq); ps += p[r]; }
      lq += ps;
      union PF { unsigned u[4]; f16x8 v; } pf0, pf1;
#pragma unroll
      for (int t = 0; t < 4; ++t) {
        pf0.u[t] = __builtin_bit_cast(unsigned, __builtin_amdgcn_cvt_pkrtz(p[2 * t], p[2 * t + 1]));
        pf1.u[t] = __builtin_bit_cast(unsigned, __builtin_amdgcn_cvt_pkrtz(p[8 + 2 * t], p[9 + 2 * t]));
      }
      acc0 = __builtin_amdgcn_mfma_f32_32x32x16_f16(vf[0], pf0.v, acc0, 0, 0, 0);
      acc0 = __builtin_amdgcn_mfma_f32_32x32x16_f16(vf[1], pf1.v, acc0, 0, 0, 0);
      acc1 = __builtin_amdgcn_mfma_f32_32x32x16_f16(vf[2], pf0.v, acc1, 0, 0, 0);
      acc1 = __builtin_amdgcn_mfma_f32_32x32x16_f16(vf[3], pf1.v, acc1, 0, 0, 0);
    }

    float ltot = lq + __shfl_xor(lq, 32, 64);
    float inv = 1.0f / ltot;
    f16* op = AO + ((size_t)(b * 2048 + irow)) * 1024 + h * 64;
#pragma unroll
    for (int t = 0; t < 4; ++t) {
      int d0 = 8 * t + 4 * hf;
      f16x4 o0, o1;
#pragma unroll
      for (int e = 0; e < 4; ++e) {
        o0[e] = (f16)(acc0[4 * t + e] * inv);
        o1[e] = (f16)(acc1[4 * t + e] * inv);
      }
      *reinterpret_cast<f16x4*>(op + d0) = o0;
      *reinterpret_cast<f16x4*>(op + 32 + d0) = o1;
    }
  }
}

// ---------------- launcher ----------------
extern "C" void kernel_launch(void* const* d_in, const int* in_sizes, int n_in,
                              void* d_out, int out_size, void* d_ws, size_t ws_size,
                              hipStream_t stream) {
  const float* x  = (const float*)d_in[0];
  const float* Wq = (const float*)d_in[1];
  const float* Wk = (const float*)d_in[2];
  const float* Wv = (const float*)d_in[3];
  const float* Wo = (const float*)d_in[4];
  const int* amask = (const int*)d_in[5];
  const int* pE    = (const int*)d_in[6];
  const int* pSkip = (const int*)d_in[7];

  char* ws = (char*)d_ws;
  f16* xb   = (f16*)(ws);                   // x f16; dead after gemm<2> -> AO
  f16* Wqb  = (f16*)(ws + (16u << 20));
  f16* Wkb  = (f16*)(ws + (18u << 20));
  f16* Wvb  = (f16*)(ws + (20u << 20));
  f16* Wob  = (f16*)(ws + (22u << 20));
  f16* Qf   = (f16*)(ws + (24u << 20));
  f16* Kx   = (f16*)(ws + (40u << 20));
  f16* Vx   = (f16*)(ws + (56u << 20));
  float2* sctab = (float2*)(ws + (72u << 20));   // 512 KB
  unsigned* pmask = (unsigned*)(ws + (73u << 20));
  f16* AO   = xb;

  // fused: x cvt + weight cvts + sctab + pmask
  k_prep<<<6401, 256, 0, stream>>>(x, Wq, Wk, Wv, Wo, xb, Wqb, Wkb, Wvb, Wob,
                                   amask, pE, pSkip, sctab, pmask);
  // QKV projections fused with RoPE + fragment-major repack (m-slab XCD map)
  k_gemm<2><<<1536, 256, 0, stream>>>(xb, Wqb, Wkb, Wvb, Qf, Kx, Vx, sctab);
  // attention: uniform-work paired q-tiles, 1 wave per block
  k_attn<<<2048, 64, 0, stream>>>(Qf, Kx, Vx, pmask, pE, AO);
  // output projection -> fp32 d_out
  k_gemm<1><<<512, 256, 0, stream>>>(AO, Wob, Wob, Wob, d_out, d_out, d_out, nullptr);
}

// Round 16
// 166.273 us; speedup vs baseline: 1.2449x; 1.0562x over previous
//
#include <hip/hip_runtime.h>
#include <cstdint>
#include <cstddef>

typedef _Float16 f16;
typedef _Float16 f16x4 __attribute__((ext_vector_type(4)));
typedef _Float16 f16x8 __attribute__((ext_vector_type(8)));
typedef float f32x4 __attribute__((ext_vector_type(4)));
typedef float f32x16 __attribute__((ext_vector_type(16)));

#define DEVI __device__ __forceinline__

DEVI void gload_lds16(const void* g, void* l) {
  __builtin_amdgcn_global_load_lds(
      (const __attribute__((address_space(1))) void*)g,
      (__attribute__((address_space(3))) void*)l, 16, 0, 0);
}

DEVI float fexp2(float x) { return __builtin_amdgcn_exp2f(x); }

// ------------- fused prep: x cvt + 4 weight cvt + sctab + pmask ----------
__global__ void k_prep(const float* __restrict__ x,
                       const float* __restrict__ w0, const float* __restrict__ w1,
                       const float* __restrict__ w2, const float* __restrict__ w3,
                       f16* __restrict__ xb,
                       f16* __restrict__ o0, f16* __restrict__ o1,
                       f16* __restrict__ o2, f16* __restrict__ o3,
                       const int* __restrict__ amask,
                       const int* __restrict__ pE, const int* __restrict__ pSkip,
                       float2* __restrict__ sctab, unsigned* __restrict__ pmask) {
  int bb = blockIdx.x;
  if (bb < 4096) {
    int i = (bb * 256 + threadIdx.x) * 8;
    const float4* p = reinterpret_cast<const float4*>(x + i);
    float4 a = p[0], b = p[1];
    f16x8 o;
    o[0] = (f16)a.x; o[1] = (f16)a.y; o[2] = (f16)a.z; o[3] = (f16)a.w;
    o[4] = (f16)b.x; o[5] = (f16)b.y; o[6] = (f16)b.z; o[7] = (f16)b.w;
    *reinterpret_cast<f16x8*>(xb + i) = o;
  } else if (bb < 6144) {
    int seg = (bb - 4096) >> 9;
    const float* in = (seg == 0) ? w0 : (seg == 1) ? w1 : (seg == 2) ? w2 : w3;
    f16* out = (seg == 0) ? o0 : (seg == 1) ? o1 : (seg == 2) ? o2 : o3;
    int i = (((bb - 4096) & 511) * 256 + threadIdx.x) * 8;
    const float4* p = reinterpret_cast<const float4*>(in + i);
    float4 a = p[0], b = p[1];
    f16x8 o;
    o[0] = (f16)a.x; o[1] = (f16)a.y; o[2] = (f16)a.z; o[3] = (f16)a.w;
    o[4] = (f16)b.x; o[5] = (f16)b.y; o[6] = (f16)b.z; o[7] = (f16)b.w;
    *reinterpret_cast<f16x8*>(out + i) = o;
  } else if (bb < 6400) {
    int E = *pE, skip = *pSkip;
    int idx = (bb - 6144) * 256 + threadIdx.x;
    int s = idx >> 5, t = idx & 31;
    float c = 1.0f, sn = 0.0f;
    if (!(skip && s < E)) {
      int p = skip ? s - E : s;
      float inv_freq = powf(10000.0f, -(float)t / 32.0f);
      sincosf((float)p * inv_freq, &sn, &c);
    }
    sctab[idx] = make_float2(c, sn);
  } else {
    int tid = threadIdx.x;
    int b = tid >> 6, jb = tid & 63;
    unsigned bits = 0;
    for (int j = 0; j < 32; ++j)
      bits |= (amask[b * 2048 + jb * 32 + j] != 0 ? 1u : 0u) << j;
    pmask[tid] = bits;
  }
}

// ---------------- GEMM: C[M,N] = A[M,K] * B[N,K]^T ----------------
// BK=64 (m97-family), 2 LDS buffers = 64 KB, counted-vmcnt depth-1:
// iter t: STAGE(t+1) -> vmcnt(8) -> s_barrier -> 16 ds_read -> lgkmcnt(0)
// -> 32 MFMA. 16 iterations (half the barriers of BK=32), 2 blocks/CU for
// cross-block latency overlap. Swizzle: LDS 16B-unit su holds global unit
// su^(row&7) (m97 family; fragment-read conflicts accepted per m97/m98).
// 1-D grid, m-slab XCD map: xcd = lid&7 owns m-panels [xcd*8, xcd*8+8).
// MODE 1: f32 out (Wo), grid 512. MODE 2: fused QKV, grid 1536
// (z=0 rope->Qf / z=1 rope->Kx frag-major / z=2 Vx tau frag-major).
template<int MODE>
__global__ __launch_bounds__(256) void k_gemm(
    const f16* __restrict__ A,
    const f16* __restrict__ B0, const f16* __restrict__ B1, const f16* __restrict__ B2,
    void* __restrict__ C0, void* __restrict__ C1, void* __restrict__ C2,
    const float2* __restrict__ sctab) {
  constexpr int K = 1024, N = 1024;
  __shared__ char smem[65536];   // [0,32K): As x2, [32K,64K): Bs x2
  const int lid = blockIdx.x;
  const int xcd = lid & 7;
  int z, mp, n;
  if (MODE == 1) {
    int c = lid >> 3;
    mp = xcd * 8 + (c & 7);
    n = c >> 3;
    z = 0;
  } else {
    int c = lid >> 3;
    mp = xcd * 8 + (c & 7);
    n = (c >> 3) & 7;
    z = c >> 6;
  }
  const f16* B = (z == 0) ? B0 : ((z == 1) ? B1 : B2);
  const int tid = threadIdx.x;
  const int lane = tid & 63;
  const int wave = tid >> 6;
  const int wr = wave >> 1, wc = wave & 1;
  const int l15 = lane & 15, l4 = lane >> 4;
  const int m0 = mp * 128, n0 = n * 128;

  // staging: thread -> (row sr = tid>>3 in 0..31, unit su = tid&7);
  // LDS unit su holds global unit su ^ (row&7); rows sr+32k keep row&7.
  const int sr = tid >> 3, su = tid & 7;
  const int ce = (su ^ (sr & 7)) * 8;
  const f16* gA0 = A + (size_t)(m0 + sr) * K + ce;
  const f16* gB0 = B + (size_t)(n0 + sr) * K + ce;

  auto STAGE = [&](int bb, int kt) {
#pragma unroll
    for (int k = 0; k < 4; ++k)
      gload_lds16(gA0 + kt + (size_t)(32 * k) * K,
                  smem + bb * 16384 + k * 4096 + tid * 16);
#pragma unroll
    for (int k = 0; k < 4; ++k)
      gload_lds16(gB0 + kt + (size_t)(32 * k) * K,
                  smem + 32768 + bb * 16384 + k * 4096 + tid * 16);
  };

  f32x4 acc[4][4] = {};

  STAGE(0, 0);
  for (int t = 0; t < 16; ++t) {
    const int cur = t & 1;
    if (t + 1 < 16) {
      STAGE(cur ^ 1, (t + 1) * 64);
      asm volatile("s_waitcnt vmcnt(8)" ::: "memory");
    } else {
      asm volatile("s_waitcnt vmcnt(0)" ::: "memory");
    }
    __builtin_amdgcn_s_barrier();
    __builtin_amdgcn_sched_barrier(0);
#pragma unroll
    for (int kk = 0; kk < 2; ++kk) {
      f16x8 af[4], bf[4];
#pragma unroll
      for (int mi = 0; mi < 4; ++mi) {
        int r = wr * 64 + mi * 16 + l15;
        af[mi] = *reinterpret_cast<const f16x8*>(
            smem + cur * 16384 + r * 128 + (((kk * 4 + l4) ^ (r & 7)) * 16));
      }
#pragma unroll
      for (int ni = 0; ni < 4; ++ni) {
        int r = wc * 64 + ni * 16 + l15;
        bf[ni] = *reinterpret_cast<const f16x8*>(
            smem + 32768 + cur * 16384 + r * 128 + (((kk * 4 + l4) ^ (r & 7)) * 16));
      }
#pragma unroll
      for (int mi = 0; mi < 4; ++mi)
#pragma unroll
        for (int ni = 0; ni < 4; ++ni)
          acc[mi][ni] = __builtin_amdgcn_mfma_f32_16x16x32_f16(af[mi], bf[ni], acc[mi][ni], 0, 0, 0);
    }
  }

  if (MODE == 1) {
#pragma unroll
    for (int mi = 0; mi < 4; ++mi)
#pragma unroll
      for (int ni = 0; ni < 4; ++ni)
#pragma unroll
        for (int r = 0; r < 4; ++r) {
          int row = m0 + wr * 64 + mi * 16 + l4 * 4 + r;
          int col = n0 + wc * 64 + ni * 16 + l15;
          ((float*)C0)[(size_t)row * N + col] = acc[mi][ni][r];
        }
    return;
  }

  f16* Qf = (f16*)C0;
  f16* Kx = (f16*)C1;
  f16* Vx = (f16*)C2;

  if (z == 0) {
#pragma unroll
    for (int mi = 0; mi < 4; ++mi)
#pragma unroll
      for (int ni = 0; ni < 4; ++ni)
#pragma unroll
        for (int r = 0; r < 4; ++r) {
          int row = m0 + wr * 64 + mi * 16 + l4 * 4 + r;
          int col = n0 + wc * 64 + ni * 16 + l15;
          int s = row & 2047;
          int dd = col & 63;
          float val = acc[mi][ni][r];
          float pv = __shfl_xor(val, 1, 64);
          float2 cs = sctab[s * 32 + (dd >> 1)];
          val = val * cs.x + ((l15 & 1) ? pv * cs.y : -pv * cs.y);
          Qf[(size_t)row * 1024 + col] = (f16)val;
        }
    return;
  }

  __syncthreads();  // all loads landed (vmcnt(0) at t=15); reuse smem as C-tile
  f16* Ct = (f16*)smem;

  if (z == 1) {
#pragma unroll
    for (int mi = 0; mi < 4; ++mi)
#pragma unroll
      for (int ni = 0; ni < 4; ++ni)
#pragma unroll
        for (int r = 0; r < 4; ++r) {
          int sl = wr * 64 + mi * 16 + l4 * 4 + r;
          int cl = wc * 64 + ni * 16 + l15;
          int s = (m0 + sl) & 2047;
          float val = acc[mi][ni][r];
          float pv = __shfl_xor(val, 1, 64);
          float2 cs = sctab[s * 32 + ((cl & 63) >> 1)];
          val = val * cs.x + ((l15 & 1) ? pv * cs.y : -pv * cs.y);
          *(f16*)((char*)Ct + sl * 256 + (((cl >> 3) ^ (sl & 15)) << 4) + (cl & 7) * 2) = (f16)val;
        }
    __syncthreads();
#pragma unroll
    for (int it = 0; it < 8; ++it) {
      int it2 = wave * 8 + it;
      int h2 = it2 >> 4, k16 = (it2 >> 2) & 3, hf = (it2 >> 1) & 1, sh = it2 & 1;
      int sl = sh * 64 + lane;
      int cl = h2 * 64 + k16 * 16 + hf * 8;
      f16x8 v = *(const f16x8*)((const char*)Ct + sl * 256 + (((cl >> 3) ^ (sl & 15)) << 4));
      int sg = m0 + sl;
      int b = sg >> 11, s = sg & 2047;
      int h = (n0 >> 6) + h2;
      *reinterpret_cast<f16x8*>(
          Kx + (((size_t)((b * 16 + h) * 4 + k16) * 2048 + s) << 4) + hf * 8) = v;
    }
  } else {
#pragma unroll
    for (int mi = 0; mi < 4; ++mi)
#pragma unroll
      for (int ni = 0; ni < 4; ++ni) {
        int sl = wr * 64 + mi * 16 + l4 * 4;
        int cl = wc * 64 + ni * 16 + l15;
        f16x4 pk;
#pragma unroll
        for (int r = 0; r < 4; ++r) pk[r] = (f16)acc[mi][ni][r];
        *(f16x4*)((char*)Ct + cl * 256 + ((((sl >> 2) ^ (cl & 31))) << 3)) = pk;
      }
    __syncthreads();
#pragma unroll
    for (int it = 0; it < 8; ++it) {
      int it2 = wave * 8 + it;
      int hh = it2 >> 4, dh2 = (it2 >> 3) & 1, kvb = (it2 >> 1) & 3, hf = it2 & 1;
      int kh = lane >> 5, ql = lane & 31;
      int cl = hh * 64 + dh2 * 32 + ql;
      int s0 = kvb * 32 + kh * 16 + hf * 4;
      f16x4 a = *(const f16x4*)((const char*)Ct + cl * 256 + (((s0 >> 2) ^ (cl & 31)) << 3));
      f16x4 c = *(const f16x4*)((const char*)Ct + cl * 256 + ((((s0 + 8) >> 2) ^ (cl & 31)) << 3));
      f16x8 v;
#pragma unroll
      for (int e = 0; e < 4; ++e) { v[e] = a[e]; v[4 + e] = c[e]; }
      int b = m0 >> 11;
      int kvblk = ((m0 & 2047) >> 5) + kvb;
      int h = (n0 >> 6) + hh;
      size_t idx = (((size_t)(((b * 16 + h) * 64 + kvblk) * 2 + dh2) * 2 + kh) * 32 + ql) << 4;
      *reinterpret_cast<f16x8*>(Vx + idx + hf * 8) = v;
    }
  }
}

// ---------------- flash attention: uniform-work q-tile pairing ------------
// Grid 2048 x 64 threads (1 wave). Block = (bh, pr); runs the r10-exact
// tile loop twice: qt = 63-pr (heavy) then qt = pr (light) = 65 tiles/block,
// uniform across the grid -> no residency-decay tail.
__global__ __launch_bounds__(64) void k_attn(
    const f16* __restrict__ Q, const f16* __restrict__ Kx, const f16* __restrict__ Vx,
    const unsigned* __restrict__ pmask, const int* __restrict__ pE,
    f16* __restrict__ AO) {
  const int lid = (blockIdx.x & 7) * 256 + (blockIdx.x >> 3);  // XCD swizzle (2048%8==0)
  const int bh = lid >> 5;                                     // 8 bh per XCD
  const int pr = lid & 31;
  const int b = bh >> 4, h = bh & 15;
  const int lane = threadIdx.x;
  const int ql = lane & 31;
  const int hf = lane >> 5;
  const int E = *pE;
  const int ekv = (E + 31) >> 5;
  constexpr float SCALE = 0.125f * 1.44269504088896f;  // dh^-0.5 * log2(e)

#pragma unroll 1
  for (int half = 0; half < 2; ++half) {
    const int qt = half ? pr : 63 - pr;
    const int irow = qt * 32 + ql;

    f16x8 qf[4];
    {
      const f16* qp = Q + ((size_t)(b * 2048 + irow)) * 1024 + h * 64 + hf * 8;
#pragma unroll
      for (int k16 = 0; k16 < 4; ++k16) {
        f16x8 v = *reinterpret_cast<const f16x8*>(qp + k16 * 16);
#pragma unroll
        for (int e = 0; e < 8; ++e) v[e] = (f16)((float)v[e] * SCALE);
        qf[k16] = v;
      }
    }

    f32x16 acc0 = {}, acc1 = {};
    float mq = -1e30f, lq = 0.f;

    int nkv = qt + 1;
    if (ekv > nkv) nkv = ekv;
    if (nkv > 64) nkv = 64;

    f16x8 kf[4];
#pragma unroll
    for (int k16 = 0; k16 < 4; ++k16)
      kf[k16] = *reinterpret_cast<const f16x8*>(
          Kx + (((size_t)((bh * 4 + k16) * 2048 + ql)) << 4) + hf * 8);

    for (int jb = 0; jb < nkv; ++jb) {
      const int kv0 = jb * 32;
      f32x16 st = {};
#pragma unroll
      for (int k16 = 0; k16 < 4; ++k16)
        st = __builtin_amdgcn_mfma_f32_32x32x16_f16(kf[k16], qf[k16], st, 0, 0, 0);
      f16x8 vf[4];
#pragma unroll
      for (int dh2 = 0; dh2 < 2; ++dh2)
#pragma unroll
        for (int kh = 0; kh < 2; ++kh)
          vf[dh2 * 2 + kh] = *reinterpret_cast<const f16x8*>(
              Vx + (((size_t)((((bh * 64 + jb) * 2 + dh2) * 2 + kh) * 32 + ql)) << 4) + hf * 8);
      unsigned pm = pmask[b * 64 + jb];
      if (jb + 1 < nkv) {
#pragma unroll
        for (int k16 = 0; k16 < 4; ++k16)
          kf[k16] = *reinterpret_cast<const f16x8*>(
              Kx + (((size_t)((bh * 4 + k16) * 2048 + kv0 + 32 + ql)) << 4) + hf * 8);
      }
      bool full = ((jb < qt) || ((jb + 1) * 32 <= E)) && (pm == 0xffffffffu);
      if (!full) {
#pragma unroll
        for (int r = 0; r < 16; ++r) {
          int kvl = (r & 3) + 8 * (r >> 2) + 4 * hf;
          int jcol = kv0 + kvl;
          bool vis = ((jcol <= irow) || (jcol < E)) && (((pm >> kvl) & 1u) != 0);
          st[r] = vis ? st[r] : -1e30f;
        }
      }
      float t0 = fmaxf(fmaxf(st[0], st[1]), st[2]);
      float t1 = fmaxf(fmaxf(st[3], st[4]), st[5]);
      float t2 = fmaxf(fmaxf(st[6], st[7]), st[8]);
      float t3 = fmaxf(fmaxf(st[9], st[10]), st[11]);
      float t4 = fmaxf(fmaxf(st[12], st[13]), st[14]);
      float mt = fmaxf(fmaxf(t0, t1), t2);
      mt = fmaxf(fmaxf(mt, t3), fmaxf(t4, st[15]));
      mt = fmaxf(mt, __shfl_xor(mt, 32, 64));
      if (!__all(mt - mq <= 8.0f)) {
        float mnew = fmaxf(mq, mt);
        float alpha = fexp2(mq - mnew);
        lq *= alpha;
#pragma unroll
        for (int r = 0; r < 16; ++r) { acc0[r] *= alpha; acc1[r] *= alpha; }
        mq = mnew;
      }
      float p[16];
      float ps = 0.f;
#pragma unroll
      for (int r = 0; r < 16; ++r) { p[r] = fexp2(st[r] - mq); ps += p[r]; }
      lq += ps;
      union PF { unsigned u[4]; f16x8 v; } pf0, pf1;
#pragma unroll
      for (int t = 0; t < 4; ++t) {
        pf0.u[t] = __builtin_bit_cast(unsigned, __builtin_amdgcn_cvt_pkrtz(p[2 * t], p[2 * t + 1]));
        pf1.u[t] = __builtin_bit_cast(unsigned, __builtin_amdgcn_cvt_pkrtz(p[8 + 2 * t], p[9 + 2 * t]));
      }
      acc0 = __builtin_amdgcn_mfma_f32_32x32x16_f16(vf[0], pf0.v, acc0, 0, 0, 0);
      acc0 = __builtin_amdgcn_mfma_f32_32x32x16_f16(vf[1], pf1.v, acc0, 0, 0, 0);
      acc1 = __builtin_amdgcn_mfma_f32_32x32x16_f16(vf[2], pf0.v, acc1, 0, 0, 0);
      acc1 = __builtin_amdgcn_mfma_f32_32x32x16_f16(vf[3], pf1.v, acc1, 0, 0, 0);
    }

    float ltot = lq + __shfl_xor(lq, 32, 64);
    float inv = 1.0f / ltot;
    f16* op = AO + ((size_t)(b * 2048 + irow)) * 1024 + h * 64;
#pragma unroll
    for (int t = 0; t < 4; ++t) {
      int d0 = 8 * t + 4 * hf;
      f16x4 o0, o1;
#pragma unroll
      for (int e = 0; e < 4; ++e) {
        o0[e] = (f16)(acc0[4 * t + e] * inv);
        o1[e] = (f16)(acc1[4 * t + e] * inv);
      }
      *reinterpret_cast<f16x4*>(op + d0) = o0;
      *reinterpret_cast<f16x4*>(op + 32 + d0) = o1;
    }
  }
}

// ---------------- launcher ----------------
extern "C" void kernel_launch(void* const* d_in, const int* in_sizes, int n_in,
                              void* d_out, int out_size, void* d_ws, size_t ws_size,
                              hipStream_t stream) {
  const float* x  = (const float*)d_in[0];
  const float* Wq = (const float*)d_in[1];
  const float* Wk = (const float*)d_in[2];
  const float* Wv = (const float*)d_in[3];
  const float* Wo = (const float*)d_in[4];
  const int* amask = (const int*)d_in[5];
  const int* pE    = (const int*)d_in[6];
  const int* pSkip = (const int*)d_in[7];

  char* ws = (char*)d_ws;
  f16* xb   = (f16*)(ws);                   // x f16; dead after gemm<2> -> AO
  f16* Wqb  = (f16*)(ws + (16u << 20));
  f16* Wkb  = (f16*)(ws + (18u << 20));
  f16* Wvb  = (f16*)(ws + (20u << 20));
  f16* Wob  = (f16*)(ws + (22u << 20));
  f16* Qf   = (f16*)(ws + (24u << 20));
  f16* Kx   = (f16*)(ws + (40u << 20));
  f16* Vx   = (f16*)(ws + (56u << 20));
  float2* sctab = (float2*)(ws + (72u << 20));   // 512 KB
  unsigned* pmask = (unsigned*)(ws + (73u << 20));
  f16* AO   = xb;

  // fused: x cvt + weight cvts + sctab + pmask
  k_prep<<<6401, 256, 0, stream>>>(x, Wq, Wk, Wv, Wo, xb, Wqb, Wkb, Wvb, Wob,
                                   amask, pE, pSkip, sctab, pmask);
  // QKV projections fused with RoPE + fragment-major repack (m-slab XCD map)
  k_gemm<2><<<1536, 256, 0, stream>>>(xb, Wqb, Wkb, Wvb, Qf, Kx, Vx, sctab);
  // attention: uniform-work paired q-tiles, 1 wave per block
  k_attn<<<2048, 64, 0, stream>>>(Qf, Kx, Vx, pmask, pE, AO);
  // output projection -> fp32 d_out
  k_gemm<1><<<512, 256, 0, stream>>>(AO, Wob, Wob, Wob, d_out, d_out, d_out, nullptr);
}